// Round 1
// baseline (2099.505 us; speedup 1.0000x reference)
//
#include <hip/hip_runtime.h>
#include <math.h>

#define CC 256
#define KK 8
#define MM 6
#define SS 3
#define NVOX 12000
#define VPB 2

__device__ __forceinline__ float4 f4add(const float4 a, const float4 b) {
  return make_float4(a.x + b.x, a.y + b.y, a.z + b.z, a.w + b.w);
}

__global__ __launch_bounds__(256)
void stftr_fused(const float* __restrict__ ptsf, const float* __restrict__ ptspe,
                 const float* __restrict__ knnf, const float* __restrict__ knnpe,
                 const float* __restrict__ sfeat, const int* __restrict__ maskp,
                 const float* __restrict__ Wq_t, const float* __restrict__ Wk_t,
                 const float* __restrict__ Wv_t, const float* __restrict__ Wo_t,
                 const float* __restrict__ bq_t, const float* __restrict__ bk_t,
                 const float* __restrict__ bv_t, const float* __restrict__ bo_t,
                 const float* __restrict__ Wq_c, const float* __restrict__ Wk_c,
                 const float* __restrict__ Wv_c, const float* __restrict__ Wo_c,
                 const float* __restrict__ bq_c, const float* __restrict__ bk_c,
                 const float* __restrict__ bv_c, const float* __restrict__ bo_c,
                 float* __restrict__ out)
{
  __shared__ __align__(16) float qb[VPB][CC];        // q_base rows
  __shared__ __align__(16) float rows[VPB * KK * CC]; // kv rows; reused for sampled rows
  __shared__ __align__(16) float ctxl[VPB][CC];
  __shared__ __align__(16) float outl[VPB][CC];
  __shared__ float red[VPB][KK][4];

  const int tid = threadIdx.x;
  const int d = tid;                 // output channel owned by this thread
  const int wid = tid >> 6;
  const int lane = tid & 63;
  const int v0 = blockIdx.x * VPB;
  const float scale = 0.0625f;       // 1/sqrt(256)

  // stage q_base = pts_query_feats + pts_query_pe for VPB voxels (contiguous)
  if (tid < VPB * CC / 4) {
    const float4* a = (const float4*)(ptsf + (size_t)v0 * CC);
    const float4* b = (const float4*)(ptspe + (size_t)v0 * CC);
    ((float4*)qb)[tid] = f4add(a[tid], b[tid]);
  }

  float acc_out[VPB] = {0.f, 0.f};   // temporal output summed over s (this thread's dim d)

  for (int s = 0; s < SS; ++s) {
    __syncthreads();  // rows/ctxl from previous iteration fully consumed
    {
      // stage kv = knn_feat + knn_pe : VPB*K*C contiguous floats
      const float4* f4 = (const float4*)(knnf + ((size_t)s * NVOX + v0) * (KK * CC));
      const float4* p4 = (const float4*)(knnpe + ((size_t)s * NVOX + v0) * (KK * CC));
      #pragma unroll
      for (int it = 0; it < (VPB * KK * CC / 4) / 256; ++it) {
        const int t = tid + it * 256;
        ((float4*)rows)[t] = f4add(f4[t], p4[t]);
      }
    }
    __syncthreads();

    const float* wq = Wq_t + (size_t)s * CC * CC;
    const float* wk = Wk_t + (size_t)s * CC * CC;
    const float* wv = Wv_t + (size_t)s * CC * CC;

    float aq[VPB];
    float ak[VPB][KK];
    float av[VPB][KK];
    #pragma unroll
    for (int j = 0; j < VPB; ++j) {
      aq[j] = 0.f;
      #pragma unroll
      for (int r = 0; r < KK; ++r) { ak[j][r] = 0.f; av[j][r] = 0.f; }
    }

    // projections: thread d computes q[j][d], k[j][r][d], v[j][r][d]
    #pragma unroll 2
    for (int c = 0; c < CC; c += 4) {
      float w_q[4], w_k[4], w_v[4];
      #pragma unroll
      for (int i = 0; i < 4; ++i) {
        w_q[i] = wq[(c + i) * CC + d];
        w_k[i] = wk[(c + i) * CC + d];
        w_v[i] = wv[(c + i) * CC + d];
      }
      #pragma unroll
      for (int j = 0; j < VPB; ++j) {
        const float4 qv = *(const float4*)&qb[j][c];
        const float* qp = (const float*)&qv;
        #pragma unroll
        for (int i = 0; i < 4; ++i) aq[j] += qp[i] * w_q[i];
        #pragma unroll
        for (int r = 0; r < KK; ++r) {
          const float4 kv = *(const float4*)&rows[(j * KK + r) * CC + c];
          const float* kp = (const float*)&kv;
          #pragma unroll
          for (int i = 0; i < 4; ++i) {
            ak[j][r] += kp[i] * w_k[i];
            av[j][r] += kp[i] * w_v[i];
          }
        }
      }
    }

    {
      const float bq = bq_t[s * CC + d];
      const float bk = bk_t[s * CC + d];
      const float bv = bv_t[s * CC + d];
      #pragma unroll
      for (int j = 0; j < VPB; ++j) {
        aq[j] += bq;
        #pragma unroll
        for (int r = 0; r < KK; ++r) { ak[j][r] += bk; av[j][r] += bv; }
      }
    }

    // scores[j][r] = sum_d q*k : wave shfl reduce + cross-wave via LDS
    #pragma unroll
    for (int j = 0; j < VPB; ++j) {
      #pragma unroll
      for (int r = 0; r < KK; ++r) {
        float p = aq[j] * ak[j][r];
        #pragma unroll
        for (int off = 32; off > 0; off >>= 1) p += __shfl_xor(p, off, 64);
        if (lane == 0) red[j][r][wid] = p;
      }
    }
    __syncthreads();

    float cx[VPB];
    #pragma unroll
    for (int j = 0; j < VPB; ++j) {
      float sc_[KK];
      float mx = -1e30f;
      #pragma unroll
      for (int r = 0; r < KK; ++r) {
        sc_[r] = (red[j][r][0] + red[j][r][1] + red[j][r][2] + red[j][r][3]) * scale;
        mx = fmaxf(mx, sc_[r]);
      }
      float sum = 0.f;
      #pragma unroll
      for (int r = 0; r < KK; ++r) { sc_[r] = expf(sc_[r] - mx); sum += sc_[r]; }
      const float inv = 1.f / sum;
      float c_ = 0.f;
      #pragma unroll
      for (int r = 0; r < KK; ++r) c_ += sc_[r] * inv * av[j][r];
      cx[j] = c_;
    }

    #pragma unroll
    for (int j = 0; j < VPB; ++j) ctxl[j][d] = cx[j];
    __syncthreads();

    // out_s = ctx @ Wo_t[s] + bo_t[s], accumulated over s
    const float* wo = Wo_t + (size_t)s * CC * CC;
    #pragma unroll
    for (int j = 0; j < VPB; ++j) acc_out[j] += bo_t[s * CC + d];
    #pragma unroll 2
    for (int c = 0; c < CC; c += 4) {
      float w_o[4];
      #pragma unroll
      for (int i = 0; i < 4; ++i) w_o[i] = wo[(c + i) * CC + d];
      #pragma unroll
      for (int j = 0; j < VPB; ++j) {
        const float4 cv = *(const float4*)&ctxl[j][c];
        const float* cp = (const float*)&cv;
        #pragma unroll
        for (int i = 0; i < 4; ++i) acc_out[j] += cp[i] * w_o[i];
      }
    }
  }

  // ---------------- cross-sensor attention ----------------
  #pragma unroll
  for (int j = 0; j < VPB; ++j) outl[j][d] = acc_out[j];
  {
    const float4* s4 = (const float4*)(sfeat + (size_t)v0 * MM * CC);
    #pragma unroll
    for (int it = 0; it < (VPB * MM * CC / 4) / 256; ++it) {
      const int t = tid + it * 256;
      ((float4*)rows)[t] = s4[t];
    }
  }
  __syncthreads();

  float aqc[VPB];
  float akc[VPB][MM];
  float avc[VPB][MM];
  #pragma unroll
  for (int j = 0; j < VPB; ++j) {
    aqc[j] = 0.f;
    #pragma unroll
    for (int m = 0; m < MM; ++m) { akc[j][m] = 0.f; avc[j][m] = 0.f; }
  }

  #pragma unroll 2
  for (int c = 0; c < CC; c += 4) {
    float w_q[4], w_k[4], w_v[4];
    #pragma unroll
    for (int i = 0; i < 4; ++i) {
      w_q[i] = Wq_c[(c + i) * CC + d];
      w_k[i] = Wk_c[(c + i) * CC + d];
      w_v[i] = Wv_c[(c + i) * CC + d];
    }
    #pragma unroll
    for (int j = 0; j < VPB; ++j) {
      const float4 ov = *(const float4*)&outl[j][c];
      const float* op = (const float*)&ov;
      #pragma unroll
      for (int i = 0; i < 4; ++i) aqc[j] += op[i] * w_q[i];
      #pragma unroll
      for (int m = 0; m < MM; ++m) {
        const float4 sv = *(const float4*)&rows[(j * MM + m) * CC + c];
        const float* sp = (const float*)&sv;
        #pragma unroll
        for (int i = 0; i < 4; ++i) {
          akc[j][m] += sp[i] * w_k[i];
          avc[j][m] += sp[i] * w_v[i];
        }
      }
    }
  }

  {
    const float bq = bq_c[d], bk = bk_c[d], bv = bv_c[d];
    #pragma unroll
    for (int j = 0; j < VPB; ++j) {
      aqc[j] += bq;
      #pragma unroll
      for (int m = 0; m < MM; ++m) { akc[j][m] += bk; avc[j][m] += bv; }
    }
  }

  #pragma unroll
  for (int j = 0; j < VPB; ++j) {
    #pragma unroll
    for (int m = 0; m < MM; ++m) {
      float p = aqc[j] * akc[j][m];
      #pragma unroll
      for (int off = 32; off > 0; off >>= 1) p += __shfl_xor(p, off, 64);
      if (lane == 0) red[j][m][wid] = p;
    }
  }
  __syncthreads();

  float cxc[VPB];
  int validf[VPB];
  #pragma unroll
  for (int j = 0; j < VPB; ++j) {
    float scm[MM];
    int anyv = 0;
    #pragma unroll
    for (int m = 0; m < MM; ++m) {
      const int mk = maskp[(size_t)(v0 + j) * MM + m];
      anyv |= mk;
      const float sv = (red[j][m][0] + red[j][m][1] + red[j][m][2] + red[j][m][3]) * scale;
      scm[m] = mk ? sv : -1e9f;
    }
    validf[j] = anyv;
    float mx = -1e30f;
    #pragma unroll
    for (int m = 0; m < MM; ++m) mx = fmaxf(mx, scm[m]);
    float sum = 0.f;
    #pragma unroll
    for (int m = 0; m < MM; ++m) { scm[m] = expf(scm[m] - mx); sum += scm[m]; }
    const float inv = 1.f / sum;
    float c_ = 0.f;
    #pragma unroll
    for (int m = 0; m < MM; ++m) c_ += scm[m] * inv * avc[j][m];
    cxc[j] = c_;
  }

  #pragma unroll
  for (int j = 0; j < VPB; ++j) ctxl[j][d] = cxc[j];
  __syncthreads();

  float o_[VPB];
  #pragma unroll
  for (int j = 0; j < VPB; ++j) o_[j] = bo_c[d];
  #pragma unroll 2
  for (int c = 0; c < CC; c += 4) {
    float w_o[4];
    #pragma unroll
    for (int i = 0; i < 4; ++i) w_o[i] = Wo_c[(c + i) * CC + d];
    #pragma unroll
    for (int j = 0; j < VPB; ++j) {
      const float4 cv = *(const float4*)&ctxl[j][c];
      const float* cp = (const float*)&cv;
      #pragma unroll
      for (int i = 0; i < 4; ++i) o_[j] += cp[i] * w_o[i];
    }
  }
  #pragma unroll
  for (int j = 0; j < VPB; ++j)
    out[(size_t)(v0 + j) * CC + d] = validf[j] ? o_[j] : 0.f;
}

extern "C" void kernel_launch(void* const* d_in, const int* in_sizes, int n_in,
                              void* d_out, int out_size, void* d_ws, size_t ws_size,
                              hipStream_t stream) {
  const float* ptsf  = (const float*)d_in[0];
  const float* ptspe = (const float*)d_in[1];
  const float* knnf  = (const float*)d_in[2];
  const float* knnpe = (const float*)d_in[3];
  const float* sfeat = (const float*)d_in[4];
  const int*   maskp = (const int*)d_in[5];
  const float* Wq_t = (const float*)d_in[6];
  const float* Wk_t = (const float*)d_in[7];
  const float* Wv_t = (const float*)d_in[8];
  const float* Wo_t = (const float*)d_in[9];
  const float* bq_t = (const float*)d_in[10];
  const float* bk_t = (const float*)d_in[11];
  const float* bv_t = (const float*)d_in[12];
  const float* bo_t = (const float*)d_in[13];
  const float* Wq_c = (const float*)d_in[14];
  const float* Wk_c = (const float*)d_in[15];
  const float* Wv_c = (const float*)d_in[16];
  const float* Wo_c = (const float*)d_in[17];
  const float* bq_c = (const float*)d_in[18];
  const float* bk_c = (const float*)d_in[19];
  const float* bv_c = (const float*)d_in[20];
  const float* bo_c = (const float*)d_in[21];

  dim3 grid(NVOX / VPB);
  dim3 block(256);
  stftr_fused<<<grid, block, 0, stream>>>(
      ptsf, ptspe, knnf, knnpe, sfeat, maskp,
      Wq_t, Wk_t, Wv_t, Wo_t, bq_t, bk_t, bv_t, bo_t,
      Wq_c, Wk_c, Wv_c, Wo_c, bq_c, bk_c, bv_c, bo_c,
      (float*)d_out);
}

// Round 2
// 565.923 us; speedup vs baseline: 3.7099x; 3.7099x over previous
//
#include <hip/hip_runtime.h>
#include <hip/hip_bf16.h>
#include <math.h>

#define CC 256
#define KK 8
#define MM 6
#define SS 3
#define NVOX 12000
#define VB 16
#define NBLK (NVOX / VB)

// ws layout (bytes)
#define OFF_QK4   0u                    // bf16 [4][256][256] packed [c4][d][i]
#define OFF_VO4   524288u               // bf16 [4][256][256] packed
#define OFF_WKT   1048576u              // f32  [4][256][256]  WkT[d][e] = Wk[e][d]
#define OFF_BQK   2097152u              // f32  [4][256]
#define OFF_BVO   2101248u              // f32  [4][256]
#define OFF_WQBK  2105344u              // f32  [4][256]
#define OFF_CQBK  2109440u              // f32  [4]
#define WS_NEED   2109456u

__device__ __forceinline__ float4 f4add(const float4 a, const float4 b) {
  return make_float4(a.x + b.x, a.y + b.y, a.z + b.z, a.w + b.w);
}

__device__ __forceinline__ float wred(float p) {
  #pragma unroll
  for (int off = 32; off; off >>= 1) p += __shfl_xor(p, off, 64);
  return p;
}

__device__ __forceinline__ void unpack8(const uint4 wv, float* f) {
  f[0] = __uint_as_float(wv.x << 16); f[1] = __uint_as_float(wv.x & 0xffff0000u);
  f[2] = __uint_as_float(wv.y << 16); f[3] = __uint_as_float(wv.y & 0xffff0000u);
  f[4] = __uint_as_float(wv.z << 16); f[5] = __uint_as_float(wv.z & 0xffff0000u);
  f[6] = __uint_as_float(wv.w << 16); f[7] = __uint_as_float(wv.w & 0xffff0000u);
}

// acc[j][d0+dd] += sum_c in[j][c] * W[c][d0+dd]; W packed bf16 [c4][d][4]
__device__ __forceinline__ void gemm16(const float4* __restrict__ in4,
                                       const uint4* __restrict__ wmat,
                                       const int h, const int tl,
                                       float (&a0)[8], float (&a1)[8]) {
  #pragma unroll 2
  for (int c4 = 0; c4 < 64; ++c4) {
    const uint4 wv = wmat[c4 * 128 + tl];
    float wa[8];
    unpack8(wv, wa);
    #pragma unroll
    for (int jj = 0; jj < 8; ++jj) {
      const float4 q = in4[(h * 8 + jj) * 64 + c4];
      a0[jj] += q.x * wa[0] + q.y * wa[1] + q.z * wa[2] + q.w * wa[3];
      a1[jj] += q.x * wa[4] + q.y * wa[5] + q.z * wa[6] + q.w * wa[7];
    }
  }
}

// ---------------- prep kernels ----------------

__global__ __launch_bounds__(256) void prep_transpose(
    const float* __restrict__ Wk_t, const float* __restrict__ Wk_c,
    float* __restrict__ WkT) {
  __shared__ float tile[32][33];
  const int b = blockIdx.x;            // 4 * 64
  const int u = b >> 6, q = b & 63;
  const int ei0 = (q >> 3) * 32, dj0 = (q & 7) * 32;
  const float* src = (u < 3) ? (Wk_t + u * 65536) : Wk_c;
  const int tx = threadIdx.x & 31, ty = threadIdx.x >> 5;
  #pragma unroll
  for (int i = 0; i < 4; ++i) {
    const int le = ty + i * 8;
    tile[le][tx] = src[(ei0 + le) * 256 + dj0 + tx];
  }
  __syncthreads();
  #pragma unroll
  for (int i = 0; i < 4; ++i) {
    const int ld = ty + i * 8;
    WkT[u * 65536 + (dj0 + ld) * 256 + ei0 + tx] = tile[tx][ld];
  }
}

__global__ __launch_bounds__(256) void prep_fold_mm(
    const float* __restrict__ Wq_t, const float* __restrict__ Wq_c,
    const float* __restrict__ Wv_t, const float* __restrict__ Wv_c,
    const float* __restrict__ Wo_t, const float* __restrict__ Wo_c,
    const float* __restrict__ WkT,
    __hip_bfloat16* __restrict__ qk4, __hip_bfloat16* __restrict__ vo4) {
  __shared__ float xrow[256];
  const int b = blockIdx.x;            // 8 * 256
  const int u = b >> 8, c = b & 255;
  const float *X, *Y;
  __hip_bfloat16* out;
  if (u < 4) {
    X = (u < 3) ? (Wq_t + u * 65536) : Wq_c;
    Y = WkT + u * 65536;
    out = qk4 + u * 65536;
  } else {
    const int v = u - 4;
    X = (v < 3) ? (Wv_t + v * 65536) : Wv_c;
    Y = (v < 3) ? (Wo_t + v * 65536) : Wo_c;
    out = vo4 + v * 65536;
  }
  const int t = threadIdx.x;
  xrow[t] = X[c * 256 + t];
  __syncthreads();
  float acc = 0.f;
  for (int d = 0; d < 256; ++d) acc += xrow[d] * Y[d * 256 + t];
  out[((c >> 2) * 256 + t) * 4 + (c & 3)] = __float2bfloat16(acc);
}

__global__ __launch_bounds__(256) void prep_fold_vec(
    const float* __restrict__ Wq_t, const float* __restrict__ Wq_c,
    const float* __restrict__ Wo_t, const float* __restrict__ Wo_c,
    const float* __restrict__ bq_t, const float* __restrict__ bk_t,
    const float* __restrict__ bv_t, const float* __restrict__ bo_t,
    const float* __restrict__ bq_c, const float* __restrict__ bk_c,
    const float* __restrict__ bv_c, const float* __restrict__ bo_c,
    const float* __restrict__ WkT,
    float* __restrict__ bqk, float* __restrict__ bvo,
    float* __restrict__ wqbk, float* __restrict__ cqbk) {
  const int u = blockIdx.x, t = threadIdx.x;
  const float* bq = (u < 3) ? bq_t + u * 256 : bq_c;
  const float* bk = (u < 3) ? bk_t + u * 256 : bk_c;
  const float* bv = (u < 3) ? bv_t + u * 256 : bv_c;
  const float* bo = (u < 3) ? bo_t + u * 256 : bo_c;
  const float* Wq = (u < 3) ? Wq_t + u * 65536 : Wq_c;
  const float* Wo = (u < 3) ? Wo_t + u * 65536 : Wo_c;
  const float* WT = WkT + u * 65536;
  float a1 = 0.f, a2 = 0.f, a3 = 0.f;
  for (int d = 0; d < 256; ++d) {
    a1 += bq[d] * WT[d * 256 + t];
    a2 += bv[d] * Wo[d * 256 + t];
    a3 += Wq[t * 256 + d] * bk[d];
  }
  bqk[u * 256 + t] = a1;
  bvo[u * 256 + t] = a2 + bo[t];
  wqbk[u * 256 + t] = a3;
  float p = bq[t] * bk[t];
  p = wred(p);
  __shared__ float red[4];
  if ((t & 63) == 0) red[t >> 6] = p;
  __syncthreads();
  if (t == 0) cqbk[u] = red[0] + red[1] + red[2] + red[3];
}

// ---------------- main kernel ----------------

__global__ __launch_bounds__(256) void stftr_main(
    const float* __restrict__ ptsf, const float* __restrict__ ptspe,
    const float* __restrict__ knnf, const float* __restrict__ knnpe,
    const float* __restrict__ sfeat, const int* __restrict__ maskp,
    const ushort* __restrict__ qk4, const ushort* __restrict__ vo4,
    const float* __restrict__ bqk, const float* __restrict__ bvo,
    const float* __restrict__ wqbk, const float* __restrict__ cqbk,
    float* __restrict__ out) {
  __shared__ float4 qb4[VB * 64];     // q_base rows, later temporal-out rows
  __shared__ float4 u4s[VB * 64];     // U rows
  __shared__ float4 wagg4[VB * 64];   // attn-weighted aggregate rows
  __shared__ int vlds[VB];

  const int t = threadIdx.x;
  const int lane = t & 63;
  const int w = t >> 6;
  const int h = t >> 7;
  const int tl = t & 127;
  const int d0 = tl * 2;
  const int v0 = blockIdx.x * VB;
  const float scale = 0.0625f;

  // stage q_base
  {
    const float4* a4 = (const float4*)(ptsf + (size_t)v0 * CC);
    const float4* b4 = (const float4*)(ptspe + (size_t)v0 * CC);
    #pragma unroll
    for (int it = 0; it < 4; ++it) {
      const int idx = t + it * 256;
      qb4[idx] = f4add(a4[idx], b4[idx]);
    }
  }

  float o0[8], o1[8];
  #pragma unroll
  for (int jj = 0; jj < 8; ++jj) { o0[jj] = 0.f; o1[jj] = 0.f; }

  const float4* kfp = (const float4*)knnf;
  const float4* kpp = (const float4*)knnpe;

  for (int s = 0; s < SS; ++s) {
    __syncthreads();  // A: qb staged / previous-iter wagg consumers done
    // GEMM1: U = Qb @ Wqk_s + bqk_s
    float u0[8], u1[8];
    {
      const float2 bb = *(const float2*)(bqk + s * 256 + d0);
      #pragma unroll
      for (int jj = 0; jj < 8; ++jj) { u0[jj] = bb.x; u1[jj] = bb.y; }
    }
    gemm16(qb4, (const uint4*)qk4 + (size_t)s * 8192, h, tl, u0, u1);
    {
      float* uf = (float*)u4s;
      #pragma unroll
      for (int jj = 0; jj < 8; ++jj) {
        uf[(h * 8 + jj) * 256 + d0] = u0[jj];
        uf[(h * 8 + jj) * 256 + d0 + 1] = u1[jj];
      }
    }
    __syncthreads();  // B: U visible

    // per-wave voxel pass: scores -> softmax (in regs) -> aggregate
    {
      const float4 wqb4 = ((const float4*)(wqbk + s * 256))[lane];
      const float cq = cqbk[s];
      #pragma unroll
      for (int jj2 = 0; jj2 < 4; ++jj2) {
        const int j = w * 4 + jj2;
        const int g = v0 + j;
        const float4 qv = qb4[j * 64 + lane];
        float tj = qv.x * wqb4.x + qv.y * wqb4.y + qv.z * wqb4.z + qv.w * wqb4.w;
        tj = wred(tj) + cq;
        const float4 u4 = u4s[j * 64 + lane];
        const size_t rb = ((size_t)(s * NVOX + g)) * (KK * 64) + lane;
        float sc[KK];
        #pragma unroll
        for (int r = 0; r < KK; ++r) {
          const float4 kf = kfp[rb + r * 64];
          const float4 kp = kpp[rb + r * 64];
          const float4 sm = f4add(kf, kp);
          float p = sm.x * u4.x + sm.y * u4.y + sm.z * u4.z + sm.w * u4.w;
          p = wred(p);
          sc[r] = (p + tj) * scale;
        }
        float mx = sc[0];
        #pragma unroll
        for (int r = 1; r < KK; ++r) mx = fmaxf(mx, sc[r]);
        float e[KK], sum = 0.f;
        #pragma unroll
        for (int r = 0; r < KK; ++r) { e[r] = __expf(sc[r] - mx); sum += e[r]; }
        const float inv = 1.f / sum;
        float4 acc = make_float4(0.f, 0.f, 0.f, 0.f);
        #pragma unroll
        for (int r = 0; r < KK; ++r) {
          const float a = e[r] * inv;
          const float4 kf = kfp[rb + r * 64];
          const float4 kp = kpp[rb + r * 64];
          acc.x += a * (kf.x + kp.x);
          acc.y += a * (kf.y + kp.y);
          acc.z += a * (kf.z + kp.z);
          acc.w += a * (kf.w + kp.w);
        }
        wagg4[j * 64 + lane] = acc;
      }
    }
    __syncthreads();  // C: wagg visible

    // GEMM2: outT += Wagg @ Wvo_s + bvo_s
    {
      const float2 bb = *(const float2*)(bvo + s * 256 + d0);
      #pragma unroll
      for (int jj = 0; jj < 8; ++jj) { o0[jj] += bb.x; o1[jj] += bb.y; }
    }
    gemm16(wagg4, (const uint4*)vo4 + (size_t)s * 8192, h, tl, o0, o1);
  }

  // ---------------- cross-sensor ----------------
  __syncthreads();  // D
  {
    float* qf = (float*)qb4;   // reuse for temporal-out rows
    #pragma unroll
    for (int jj = 0; jj < 8; ++jj) {
      qf[(h * 8 + jj) * 256 + d0] = o0[jj];
      qf[(h * 8 + jj) * 256 + d0 + 1] = o1[jj];
    }
  }
  __syncthreads();  // E

  float c0[8], c1[8];
  {
    const float2 bb = *(const float2*)(bqk + 3 * 256 + d0);
    #pragma unroll
    for (int jj = 0; jj < 8; ++jj) { c0[jj] = bb.x; c1[jj] = bb.y; }
  }
  gemm16(qb4, (const uint4*)qk4 + (size_t)3 * 8192, h, tl, c0, c1);
  {
    float* uf = (float*)u4s;
    #pragma unroll
    for (int jj = 0; jj < 8; ++jj) {
      uf[(h * 8 + jj) * 256 + d0] = c0[jj];
      uf[(h * 8 + jj) * 256 + d0 + 1] = c1[jj];
    }
  }
  __syncthreads();  // F

  {
    const float4 wqb4 = ((const float4*)(wqbk + 3 * 256))[lane];
    const float cq = cqbk[3];
    const float4* sfp = (const float4*)sfeat;
    #pragma unroll
    for (int jj2 = 0; jj2 < 4; ++jj2) {
      const int j = w * 4 + jj2;
      const int g = v0 + j;
      const float4 ov = qb4[j * 64 + lane];
      float tj = ov.x * wqb4.x + ov.y * wqb4.y + ov.z * wqb4.z + ov.w * wqb4.w;
      tj = wred(tj) + cq;
      const float4 u4 = u4s[j * 64 + lane];
      const size_t sb = (size_t)g * (MM * 64) + lane;
      float scm[MM];
      int vldv = 0;
      #pragma unroll
      for (int m = 0; m < MM; ++m) {
        const float4 sf = sfp[sb + m * 64];
        float p = sf.x * u4.x + sf.y * u4.y + sf.z * u4.z + sf.w * u4.w;
        p = wred(p);
        const int mk = maskp[g * MM + m];
        vldv |= mk;
        scm[m] = mk ? (p + tj) * scale : -1e9f;
      }
      float mx = scm[0];
      #pragma unroll
      for (int m = 1; m < MM; ++m) mx = fmaxf(mx, scm[m]);
      float e[MM], sum = 0.f;
      #pragma unroll
      for (int m = 0; m < MM; ++m) { e[m] = __expf(scm[m] - mx); sum += e[m]; }
      const float inv = 1.f / sum;
      float4 acc = make_float4(0.f, 0.f, 0.f, 0.f);
      #pragma unroll
      for (int m = 0; m < MM; ++m) {
        const float a = e[m] * inv;
        const float4 sf = sfp[sb + m * 64];
        acc.x += a * sf.x; acc.y += a * sf.y; acc.z += a * sf.z; acc.w += a * sf.w;
      }
      wagg4[j * 64 + lane] = acc;
      if (lane == 0) vlds[j] = vldv;
    }
  }
  __syncthreads();  // G

  float f0[8], f1[8];
  {
    const float2 bb = *(const float2*)(bvo + 3 * 256 + d0);
    #pragma unroll
    for (int jj = 0; jj < 8; ++jj) { f0[jj] = bb.x; f1[jj] = bb.y; }
  }
  gemm16(wagg4, (const uint4*)vo4 + (size_t)3 * 8192, h, tl, f0, f1);

  #pragma unroll
  for (int jj = 0; jj < 8; ++jj) {
    const int j = h * 8 + jj;
    const int g = v0 + j;
    const int vl = vlds[j];
    float2 r;
    r.x = vl ? f0[jj] : 0.f;
    r.y = vl ? f1[jj] : 0.f;
    *(float2*)(out + (size_t)g * CC + d0) = r;
  }
}

extern "C" void kernel_launch(void* const* d_in, const int* in_sizes, int n_in,
                              void* d_out, int out_size, void* d_ws, size_t ws_size,
                              hipStream_t stream) {
  const float* ptsf  = (const float*)d_in[0];
  const float* ptspe = (const float*)d_in[1];
  const float* knnf  = (const float*)d_in[2];
  const float* knnpe = (const float*)d_in[3];
  const float* sfeat = (const float*)d_in[4];
  const int*   maskp = (const int*)d_in[5];
  const float* Wq_t = (const float*)d_in[6];
  const float* Wk_t = (const float*)d_in[7];
  const float* Wv_t = (const float*)d_in[8];
  const float* Wo_t = (const float*)d_in[9];
  const float* bq_t = (const float*)d_in[10];
  const float* bk_t = (const float*)d_in[11];
  const float* bv_t = (const float*)d_in[12];
  const float* bo_t = (const float*)d_in[13];
  const float* Wq_c = (const float*)d_in[14];
  const float* Wk_c = (const float*)d_in[15];
  const float* Wv_c = (const float*)d_in[16];
  const float* Wo_c = (const float*)d_in[17];
  const float* bq_c = (const float*)d_in[18];
  const float* bk_c = (const float*)d_in[19];
  const float* bv_c = (const float*)d_in[20];
  const float* bo_c = (const float*)d_in[21];

  if (ws_size < WS_NEED) return;
  char* ws = (char*)d_ws;
  __hip_bfloat16* qk4 = (__hip_bfloat16*)(ws + OFF_QK4);
  __hip_bfloat16* vo4 = (__hip_bfloat16*)(ws + OFF_VO4);
  float* WkT  = (float*)(ws + OFF_WKT);
  float* bqk  = (float*)(ws + OFF_BQK);
  float* bvo  = (float*)(ws + OFF_BVO);
  float* wqbk = (float*)(ws + OFF_WQBK);
  float* cqbk = (float*)(ws + OFF_CQBK);

  prep_transpose<<<256, 256, 0, stream>>>(Wk_t, Wk_c, WkT);
  prep_fold_vec<<<4, 256, 0, stream>>>(Wq_t, Wq_c, Wo_t, Wo_c,
                                       bq_t, bk_t, bv_t, bo_t,
                                       bq_c, bk_c, bv_c, bo_c,
                                       WkT, bqk, bvo, wqbk, cqbk);
  prep_fold_mm<<<2048, 256, 0, stream>>>(Wq_t, Wq_c, Wv_t, Wv_c, Wo_t, Wo_c,
                                         WkT, qk4, vo4);
  stftr_main<<<NBLK, 256, 0, stream>>>(
      ptsf, ptspe, knnf, knnpe, sfeat, maskp,
      (const ushort*)qk4, (const ushort*)vo4, bqk, bvo, wqbk, cqbk,
      (float*)d_out);
}

// Round 3
// 442.776 us; speedup vs baseline: 4.7417x; 1.2781x over previous
//
#include <hip/hip_runtime.h>
#include <hip/hip_bf16.h>
#include <math.h>

#define CC 256
#define KK 8
#define MM 6
#define SS 3
#define NVOX 12000
#define VB 16
#define NBLK (NVOX / VB)

// ---- ws layout (bytes) ----
#define OFF_QK4   0u           // bf16 4x[64c4][256d][4] packed
#define OFF_VO4   524288u      // new: temporal concat [192c4][256][4]; old: 4x256x256
#define OFF_VO4C  917504u      // new layout only: cross [64c4][256][4]
#define OFF_WKT   1048576u
#define OFF_BQK   2097152u
#define OFF_BVO   2101248u
#define OFF_WQBK  2105344u     // fallback only
#define OFF_CQBK  2109440u     // fallback only
#define WS_NEED_OLD 2109456u
#define OFF_U     2109504u                     // bf16 36000x256
#define OFF_WAGG  (OFF_U + 18432000u)          // bf16 36000x256
#define OFF_UC    (OFF_WAGG + 18432000u)       // bf16 12000x256
#define OFF_CAGG  (OFF_UC + 6144000u)          // bf16 12000x256
#define OFF_VALID (OFF_CAGG + 6144000u)        // int 12000
#define WS_NEED_NEW (OFF_VALID + 48000u)

__device__ __forceinline__ float4 f4add(const float4 a, const float4 b) {
  return make_float4(a.x + b.x, a.y + b.y, a.z + b.z, a.w + b.w);
}

__device__ __forceinline__ float wred(float p) {
  #pragma unroll
  for (int off = 32; off; off >>= 1) p += __shfl_xor(p, off, 64);
  return p;
}

__device__ __forceinline__ void unpack8(const uint4 wv, float* f) {
  f[0] = __uint_as_float(wv.x << 16); f[1] = __uint_as_float(wv.x & 0xffff0000u);
  f[2] = __uint_as_float(wv.y << 16); f[3] = __uint_as_float(wv.y & 0xffff0000u);
  f[4] = __uint_as_float(wv.z << 16); f[5] = __uint_as_float(wv.z & 0xffff0000u);
  f[6] = __uint_as_float(wv.w << 16); f[7] = __uint_as_float(wv.w & 0xffff0000u);
}

__device__ __forceinline__ uint f2bf(float x) {  // RNE to bf16 bits
  const uint u = __float_as_uint(x);
  return (u + 0x7fffu + ((u >> 16) & 1u)) >> 16;
}
__device__ __forceinline__ uint bfpack(float a, float b) {
  return (f2bf(b) << 16) | f2bf(a);
}
__device__ __forceinline__ float bflo(uint w) { return __uint_as_float(w << 16); }
__device__ __forceinline__ float bfhi(uint w) { return __uint_as_float(w & 0xffff0000u); }

// rows 16, depth D4*4; input f32 LDS row-major; weights bf16 packed [c4][d][4]
template<int D4>
__device__ __forceinline__ void gemm16(const float4* __restrict__ in4,
                                       const uint4* __restrict__ wmat,
                                       const int h, const int tl,
                                       float (&a0)[8], float (&a1)[8]) {
  #pragma unroll 2
  for (int c4 = 0; c4 < D4; ++c4) {
    const uint4 wv = wmat[c4 * 128 + tl];
    float wa[8];
    unpack8(wv, wa);
    #pragma unroll
    for (int jj = 0; jj < 8; ++jj) {
      const float4 q = in4[(h * 8 + jj) * D4 + c4];
      a0[jj] += q.x * wa[0] + q.y * wa[1] + q.z * wa[2] + q.w * wa[3];
      a1[jj] += q.x * wa[4] + q.y * wa[5] + q.z * wa[6] + q.w * wa[7];
    }
  }
}

// ---------------- prep kernels ----------------

__global__ __launch_bounds__(256) void prep_transpose(
    const float* __restrict__ Wk_t, const float* __restrict__ Wk_c,
    float* __restrict__ WkT) {
  __shared__ float tile[32][33];
  const int b = blockIdx.x;
  const int u = b >> 6, q = b & 63;
  const int ei0 = (q >> 3) * 32, dj0 = (q & 7) * 32;
  const float* src = (u < 3) ? (Wk_t + u * 65536) : Wk_c;
  const int tx = threadIdx.x & 31, ty = threadIdx.x >> 5;
  #pragma unroll
  for (int i = 0; i < 4; ++i) {
    const int le = ty + i * 8;
    tile[le][tx] = src[(ei0 + le) * 256 + dj0 + tx];
  }
  __syncthreads();
  #pragma unroll
  for (int i = 0; i < 4; ++i) {
    const int ld = ty + i * 8;
    WkT[u * 65536 + (dj0 + ld) * 256 + ei0 + tx] = tile[tx][ld];
  }
}

__global__ __launch_bounds__(256) void prep_fold_mm(
    const float* __restrict__ Wq_t, const float* __restrict__ Wq_c,
    const float* __restrict__ Wv_t, const float* __restrict__ Wv_c,
    const float* __restrict__ Wo_t, const float* __restrict__ Wo_c,
    const float* __restrict__ WkT,
    __hip_bfloat16* __restrict__ qk4, __hip_bfloat16* __restrict__ vo4,
    __hip_bfloat16* __restrict__ vo4c, const int newlayout) {
  __shared__ float xrow[256];
  const int b = blockIdx.x;
  const int u = b >> 8, c = b & 255;
  const float *X, *Y;
  __hip_bfloat16* out;
  int cg = c;
  if (u < 4) {
    X = (u < 3) ? (Wq_t + u * 65536) : Wq_c;
    Y = WkT + u * 65536;
    out = qk4 + u * 65536;
  } else {
    const int v = u - 4;
    X = (v < 3) ? (Wv_t + v * 65536) : Wv_c;
    Y = (v < 3) ? (Wo_t + v * 65536) : Wo_c;
    if (newlayout) {
      if (v < 3) { out = vo4; cg = v * 256 + c; }
      else       { out = vo4c; }
    } else {
      out = vo4 + v * 65536;
    }
  }
  const int t = threadIdx.x;
  xrow[t] = X[c * 256 + t];
  __syncthreads();
  float acc = 0.f;
  for (int d = 0; d < 256; ++d) acc += xrow[d] * Y[d * 256 + t];
  out[((cg >> 2) * 256 + t) * 4 + (cg & 3)] = __float2bfloat16(acc);
}

__global__ __launch_bounds__(256) void prep_fold_vec(
    const float* __restrict__ Wq_t, const float* __restrict__ Wq_c,
    const float* __restrict__ Wo_t, const float* __restrict__ Wo_c,
    const float* __restrict__ bq_t, const float* __restrict__ bk_t,
    const float* __restrict__ bv_t, const float* __restrict__ bo_t,
    const float* __restrict__ bq_c, const float* __restrict__ bk_c,
    const float* __restrict__ bv_c, const float* __restrict__ bo_c,
    const float* __restrict__ WkT,
    float* __restrict__ bqk, float* __restrict__ bvo,
    float* __restrict__ wqbk, float* __restrict__ cqbk) {
  const int u = blockIdx.x, t = threadIdx.x;
  const float* bq = (u < 3) ? bq_t + u * 256 : bq_c;
  const float* bk = (u < 3) ? bk_t + u * 256 : bk_c;
  const float* bv = (u < 3) ? bv_t + u * 256 : bv_c;
  const float* bo = (u < 3) ? bo_t + u * 256 : bo_c;
  const float* Wq = (u < 3) ? Wq_t + u * 65536 : Wq_c;
  const float* Wo = (u < 3) ? Wo_t + u * 65536 : Wo_c;
  const float* WT = WkT + u * 65536;
  float a1 = 0.f, a2 = 0.f, a3 = 0.f;
  for (int d = 0; d < 256; ++d) {
    a1 += bq[d] * WT[d * 256 + t];
    a2 += bv[d] * Wo[d * 256 + t];
    a3 += Wq[t * 256 + d] * bk[d];
  }
  bqk[u * 256 + t] = a1;
  bvo[u * 256 + t] = a2 + bo[t];
  wqbk[u * 256 + t] = a3;
  float p = bq[t] * bk[t];
  p = wred(p);
  __shared__ float red[4];
  if ((t & 63) == 0) red[t >> 6] = p;
  __syncthreads();
  if (t == 0) cqbk[u] = red[0] + red[1] + red[2] + red[3];
}

// ---------------- split pipeline ----------------

// A: U[s][g][:] = (qb @ Wqk_s) + bqk_s  (bf16 out)
__global__ __launch_bounds__(256) void tproj_q(
    const float* __restrict__ ptsf, const float* __restrict__ ptspe,
    const ushort* __restrict__ qk4, const float* __restrict__ bqk,
    ushort* __restrict__ Ubf) {
  __shared__ __align__(16) float qb[VB * CC];
  const int t = threadIdx.x;
  const int h = t >> 7, tl = t & 127, d0 = tl * 2;
  const int g0 = blockIdx.x * VB;
  {
    const float4* a4 = (const float4*)(ptsf + (size_t)g0 * CC);
    const float4* b4 = (const float4*)(ptspe + (size_t)g0 * CC);
    #pragma unroll
    for (int it = 0; it < 4; ++it) {
      const int idx = t + it * 256;
      ((float4*)qb)[idx] = f4add(a4[idx], b4[idx]);
    }
  }
  __syncthreads();
  for (int s = 0; s < SS; ++s) {
    float u0[8], u1[8];
    const float2 bb = *(const float2*)(bqk + s * CC + d0);
    #pragma unroll
    for (int jj = 0; jj < 8; ++jj) { u0[jj] = bb.x; u1[jj] = bb.y; }
    gemm16<64>((const float4*)qb, (const uint4*)qk4 + (size_t)s * 8192, h, tl, u0, u1);
    #pragma unroll
    for (int jj = 0; jj < 8; ++jj) {
      const size_t g = g0 + h * 8 + jj;
      ((uint*)Ubf)[((size_t)s * NVOX + g) * 128 + tl] = bfpack(u0[jj], u1[jj]);
    }
  }
}

// B: per (s,g): scores -> softmax -> weighted kv aggregate (bf16 out)
__global__ __launch_bounds__(256) void score_t(
    const float* __restrict__ knnf, const float* __restrict__ knnpe,
    const ushort* __restrict__ Ubf, ushort* __restrict__ waggbf) {
  const int t = threadIdx.x, lane = t & 63, w = t >> 6;
  const int g = blockIdx.x * 4 + w;
  const int s = blockIdx.y;
  const size_t task = (size_t)s * NVOX + g;
  const float4* kfp = (const float4*)knnf;
  const float4* kpp = (const float4*)knnpe;
  const size_t rb = task * (KK * 64) + lane;
  float4 sm[KK];
  #pragma unroll
  for (int r = 0; r < KK; ++r) {
    const float4 kf = kfp[rb + r * 64];
    const float4 kp = kpp[rb + r * 64];
    sm[r] = f4add(kf, kp);
  }
  const uint2 uu = ((const uint2*)Ubf)[task * 64 + lane];
  const float4 u4 = make_float4(bflo(uu.x), bfhi(uu.x), bflo(uu.y), bfhi(uu.y));
  float sc[KK];
  #pragma unroll
  for (int r = 0; r < KK; ++r) {
    float p = sm[r].x * u4.x + sm[r].y * u4.y + sm[r].z * u4.z + sm[r].w * u4.w;
    sc[r] = wred(p) * 0.0625f;
  }
  float mx = sc[0];
  #pragma unroll
  for (int r = 1; r < KK; ++r) mx = fmaxf(mx, sc[r]);
  float e[KK], sum = 0.f;
  #pragma unroll
  for (int r = 0; r < KK; ++r) { e[r] = __expf(sc[r] - mx); sum += e[r]; }
  const float inv = 1.f / sum;
  float4 acc = make_float4(0.f, 0.f, 0.f, 0.f);
  #pragma unroll
  for (int r = 0; r < KK; ++r) {
    const float a = e[r] * inv;
    acc.x += a * sm[r].x; acc.y += a * sm[r].y;
    acc.z += a * sm[r].z; acc.w += a * sm[r].w;
  }
  uint2 o;
  o.x = bfpack(acc.x, acc.y);
  o.y = bfpack(acc.z, acc.w);
  ((uint2*)waggbf)[task * 64 + lane] = o;
}

// CD: tout = sum_s wagg_s @ Wvo_s + sum_s bvo_s ; Uc = tout @ Wqk_c + bqk_c
__global__ __launch_bounds__(256) void tgemm_cd(
    const ushort* __restrict__ waggbf, const ushort* __restrict__ vo4,
    const ushort* __restrict__ qk4, const float* __restrict__ bvo,
    const float* __restrict__ bqk, ushort* __restrict__ Ucbf) {
  __shared__ __align__(16) float lds[VB * 768];
  const int t = threadIdx.x, h = t >> 7, tl = t & 127, d0 = tl * 2;
  const int g0 = blockIdx.x * VB;
  const uint* wsrc = (const uint*)waggbf;
  #pragma unroll
  for (int pass = 0; pass < 24; ++pass) {
    const int f = pass * 256 + t;
    const int rl = f >> 7, u = f & 127;
    const int s = rl >> 4, j = rl & 15;
    const uint wv = wsrc[((size_t)s * NVOX + g0 + j) * 128 + u];
    lds[j * 768 + s * 256 + u * 2]     = bflo(wv);
    lds[j * 768 + s * 256 + u * 2 + 1] = bfhi(wv);
  }
  __syncthreads();
  float o0[8], o1[8];
  {
    const float2 b0 = *(const float2*)(bvo + d0);
    const float2 b1 = *(const float2*)(bvo + 256 + d0);
    const float2 b2 = *(const float2*)(bvo + 512 + d0);
    #pragma unroll
    for (int jj = 0; jj < 8; ++jj) {
      o0[jj] = b0.x + b1.x + b2.x;
      o1[jj] = b0.y + b1.y + b2.y;
    }
  }
  gemm16<192>((const float4*)lds, (const uint4*)vo4, h, tl, o0, o1);
  __syncthreads();
  #pragma unroll
  for (int jj = 0; jj < 8; ++jj) {
    const int row = h * 8 + jj;
    lds[row * 256 + d0] = o0[jj];
    lds[row * 256 + d0 + 1] = o1[jj];
  }
  __syncthreads();
  float c0[8], c1[8];
  const float2 bb = *(const float2*)(bqk + 3 * 256 + d0);
  #pragma unroll
  for (int jj = 0; jj < 8; ++jj) { c0[jj] = bb.x; c1[jj] = bb.y; }
  gemm16<64>((const float4*)lds, (const uint4*)qk4 + (size_t)3 * 8192, h, tl, c0, c1);
  #pragma unroll
  for (int jj = 0; jj < 8; ++jj) {
    const size_t g = g0 + h * 8 + jj;
    ((uint*)Ucbf)[g * 128 + tl] = bfpack(c0[jj], c1[jj]);
  }
}

// E: cross-sensor scores -> masked softmax -> aggregate
__global__ __launch_bounds__(256) void score_c(
    const float* __restrict__ sfeat, const int* __restrict__ maskp,
    const ushort* __restrict__ Ucbf, ushort* __restrict__ caggbf,
    int* __restrict__ validp) {
  const int t = threadIdx.x, lane = t & 63, w = t >> 6;
  const int g = blockIdx.x * 4 + w;
  const float4* sfp = (const float4*)sfeat;
  const size_t sb = (size_t)g * (MM * 64) + lane;
  float4 sf[MM];
  #pragma unroll
  for (int m = 0; m < MM; ++m) sf[m] = sfp[sb + m * 64];
  const uint2 uu = ((const uint2*)Ucbf)[(size_t)g * 64 + lane];
  const float4 u4 = make_float4(bflo(uu.x), bfhi(uu.x), bflo(uu.y), bfhi(uu.y));
  int mk[MM], anyv = 0;
  #pragma unroll
  for (int m = 0; m < MM; ++m) { mk[m] = maskp[(size_t)g * MM + m]; anyv |= mk[m]; }
  float scm[MM];
  #pragma unroll
  for (int m = 0; m < MM; ++m) {
    float p = sf[m].x * u4.x + sf[m].y * u4.y + sf[m].z * u4.z + sf[m].w * u4.w;
    p = wred(p);
    scm[m] = mk[m] ? p * 0.0625f : -1e9f;
  }
  float mx = scm[0];
  #pragma unroll
  for (int m = 1; m < MM; ++m) mx = fmaxf(mx, scm[m]);
  float e[MM], sum = 0.f;
  #pragma unroll
  for (int m = 0; m < MM; ++m) { e[m] = __expf(scm[m] - mx); sum += e[m]; }
  const float inv = 1.f / sum;
  float4 acc = make_float4(0.f, 0.f, 0.f, 0.f);
  #pragma unroll
  for (int m = 0; m < MM; ++m) {
    const float a = e[m] * inv;
    acc.x += a * sf[m].x; acc.y += a * sf[m].y;
    acc.z += a * sf[m].z; acc.w += a * sf[m].w;
  }
  uint2 o;
  o.x = bfpack(acc.x, acc.y);
  o.y = bfpack(acc.z, acc.w);
  ((uint2*)caggbf)[(size_t)g * 64 + lane] = o;
  if (lane == 0) validp[g] = anyv;
}

// F: out = (cagg @ Wvo_c + bvo_c) zeroed where !valid
__global__ __launch_bounds__(256) void fgemm(
    const ushort* __restrict__ caggbf, const ushort* __restrict__ vo4c,
    const float* __restrict__ bvo, const int* __restrict__ validp,
    float* __restrict__ out) {
  __shared__ __align__(16) float lds[VB * CC];
  const int t = threadIdx.x, h = t >> 7, tl = t & 127, d0 = tl * 2;
  const int g0 = blockIdx.x * VB;
  const uint* csrc = (const uint*)caggbf;
  #pragma unroll
  for (int pass = 0; pass < 8; ++pass) {
    const int f = pass * 256 + t;
    const int row = f >> 7, u = f & 127;
    const uint wv = csrc[((size_t)(g0 + row)) * 128 + u];
    lds[row * 256 + u * 2]     = bflo(wv);
    lds[row * 256 + u * 2 + 1] = bfhi(wv);
  }
  __syncthreads();
  float o0[8], o1[8];
  const float2 bb = *(const float2*)(bvo + 3 * 256 + d0);
  #pragma unroll
  for (int jj = 0; jj < 8; ++jj) { o0[jj] = bb.x; o1[jj] = bb.y; }
  gemm16<64>((const float4*)lds, (const uint4*)vo4c, h, tl, o0, o1);
  #pragma unroll
  for (int jj = 0; jj < 8; ++jj) {
    const int row = h * 8 + jj;
    const size_t g = g0 + row;
    const int vl = validp[g];
    float2 r;
    r.x = vl ? o0[jj] : 0.f;
    r.y = vl ? o1[jj] : 0.f;
    *(float2*)(out + g * CC + d0) = r;
  }
}

// ---------------- fallback fused kernel (round-2, needs only 2.1MB ws) ----------------

__global__ __launch_bounds__(256) void stftr_main(
    const float* __restrict__ ptsf, const float* __restrict__ ptspe,
    const float* __restrict__ knnf, const float* __restrict__ knnpe,
    const float* __restrict__ sfeat, const int* __restrict__ maskp,
    const ushort* __restrict__ qk4, const ushort* __restrict__ vo4,
    const float* __restrict__ bqk, const float* __restrict__ bvo,
    const float* __restrict__ wqbk, const float* __restrict__ cqbk,
    float* __restrict__ out) {
  __shared__ float4 qb4[VB * 64];
  __shared__ float4 u4s[VB * 64];
  __shared__ float4 wagg4[VB * 64];
  __shared__ int vlds[VB];

  const int t = threadIdx.x;
  const int lane = t & 63;
  const int w = t >> 6;
  const int h = t >> 7;
  const int tl = t & 127;
  const int d0 = tl * 2;
  const int v0 = blockIdx.x * VB;
  const float scale = 0.0625f;

  {
    const float4* a4 = (const float4*)(ptsf + (size_t)v0 * CC);
    const float4* b4 = (const float4*)(ptspe + (size_t)v0 * CC);
    #pragma unroll
    for (int it = 0; it < 4; ++it) {
      const int idx = t + it * 256;
      qb4[idx] = f4add(a4[idx], b4[idx]);
    }
  }

  float o0[8], o1[8];
  #pragma unroll
  for (int jj = 0; jj < 8; ++jj) { o0[jj] = 0.f; o1[jj] = 0.f; }

  const float4* kfp = (const float4*)knnf;
  const float4* kpp = (const float4*)knnpe;

  for (int s = 0; s < SS; ++s) {
    __syncthreads();
    float u0[8], u1[8];
    {
      const float2 bb = *(const float2*)(bqk + s * 256 + d0);
      #pragma unroll
      for (int jj = 0; jj < 8; ++jj) { u0[jj] = bb.x; u1[jj] = bb.y; }
    }
    gemm16<64>(qb4, (const uint4*)qk4 + (size_t)s * 8192, h, tl, u0, u1);
    {
      float* uf = (float*)u4s;
      #pragma unroll
      for (int jj = 0; jj < 8; ++jj) {
        uf[(h * 8 + jj) * 256 + d0] = u0[jj];
        uf[(h * 8 + jj) * 256 + d0 + 1] = u1[jj];
      }
    }
    __syncthreads();

    {
      const float4 wqb4 = ((const float4*)(wqbk + s * 256))[lane];
      const float cq = cqbk[s];
      #pragma unroll
      for (int jj2 = 0; jj2 < 4; ++jj2) {
        const int j = w * 4 + jj2;
        const int g = v0 + j;
        const float4 qv = qb4[j * 64 + lane];
        float tj = qv.x * wqb4.x + qv.y * wqb4.y + qv.z * wqb4.z + qv.w * wqb4.w;
        tj = wred(tj) + cq;
        const float4 u4 = u4s[j * 64 + lane];
        const size_t rb = ((size_t)(s * NVOX + g)) * (KK * 64) + lane;
        float sc[KK];
        #pragma unroll
        for (int r = 0; r < KK; ++r) {
          const float4 kf = kfp[rb + r * 64];
          const float4 kp = kpp[rb + r * 64];
          const float4 smv = f4add(kf, kp);
          float p = smv.x * u4.x + smv.y * u4.y + smv.z * u4.z + smv.w * u4.w;
          p = wred(p);
          sc[r] = (p + tj) * scale;
        }
        float mx = sc[0];
        #pragma unroll
        for (int r = 1; r < KK; ++r) mx = fmaxf(mx, sc[r]);
        float e[KK], sum = 0.f;
        #pragma unroll
        for (int r = 0; r < KK; ++r) { e[r] = __expf(sc[r] - mx); sum += e[r]; }
        const float inv = 1.f / sum;
        float4 acc = make_float4(0.f, 0.f, 0.f, 0.f);
        #pragma unroll
        for (int r = 0; r < KK; ++r) {
          const float a = e[r] * inv;
          const float4 kf = kfp[rb + r * 64];
          const float4 kp = kpp[rb + r * 64];
          acc.x += a * (kf.x + kp.x);
          acc.y += a * (kf.y + kp.y);
          acc.z += a * (kf.z + kp.z);
          acc.w += a * (kf.w + kp.w);
        }
        wagg4[j * 64 + lane] = acc;
      }
    }
    __syncthreads();

    {
      const float2 bb = *(const float2*)(bvo + s * 256 + d0);
      #pragma unroll
      for (int jj = 0; jj < 8; ++jj) { o0[jj] += bb.x; o1[jj] += bb.y; }
    }
    gemm16<64>(wagg4, (const uint4*)vo4 + (size_t)s * 8192, h, tl, o0, o1);
  }

  __syncthreads();
  {
    float* qf = (float*)qb4;
    #pragma unroll
    for (int jj = 0; jj < 8; ++jj) {
      qf[(h * 8 + jj) * 256 + d0] = o0[jj];
      qf[(h * 8 + jj) * 256 + d0 + 1] = o1[jj];
    }
  }
  __syncthreads();

  float c0[8], c1[8];
  {
    const float2 bb = *(const float2*)(bqk + 3 * 256 + d0);
    #pragma unroll
    for (int jj = 0; jj < 8; ++jj) { c0[jj] = bb.x; c1[jj] = bb.y; }
  }
  gemm16<64>(qb4, (const uint4*)qk4 + (size_t)3 * 8192, h, tl, c0, c1);
  {
    float* uf = (float*)u4s;
    #pragma unroll
    for (int jj = 0; jj < 8; ++jj) {
      uf[(h * 8 + jj) * 256 + d0] = c0[jj];
      uf[(h * 8 + jj) * 256 + d0 + 1] = c1[jj];
    }
  }
  __syncthreads();

  {
    const float4 wqb4 = ((const float4*)(wqbk + 3 * 256))[lane];
    const float cq = cqbk[3];
    const float4* sfp = (const float4*)sfeat;
    #pragma unroll
    for (int jj2 = 0; jj2 < 4; ++jj2) {
      const int j = w * 4 + jj2;
      const int g = v0 + j;
      const float4 ov = qb4[j * 64 + lane];
      float tj = ov.x * wqb4.x + ov.y * wqb4.y + ov.z * wqb4.z + ov.w * wqb4.w;
      tj = wred(tj) + cq;
      const float4 u4 = u4s[j * 64 + lane];
      const size_t sb = (size_t)g * (MM * 64) + lane;
      float scm[MM];
      int vldv = 0;
      #pragma unroll
      for (int m = 0; m < MM; ++m) {
        const float4 sfv = sfp[sb + m * 64];
        float p = sfv.x * u4.x + sfv.y * u4.y + sfv.z * u4.z + sfv.w * u4.w;
        p = wred(p);
        const int mk = maskp[g * MM + m];
        vldv |= mk;
        scm[m] = mk ? (p + tj) * scale : -1e9f;
      }
      float mx = scm[0];
      #pragma unroll
      for (int m = 1; m < MM; ++m) mx = fmaxf(mx, scm[m]);
      float e[MM], sum = 0.f;
      #pragma unroll
      for (int m = 0; m < MM; ++m) { e[m] = __expf(scm[m] - mx); sum += e[m]; }
      const float inv = 1.f / sum;
      float4 acc = make_float4(0.f, 0.f, 0.f, 0.f);
      #pragma unroll
      for (int m = 0; m < MM; ++m) {
        const float a = e[m] * inv;
        const float4 sfv = sfp[sb + m * 64];
        acc.x += a * sfv.x; acc.y += a * sfv.y; acc.z += a * sfv.z; acc.w += a * sfv.w;
      }
      wagg4[j * 64 + lane] = acc;
      if (lane == 0) vlds[j] = vldv;
    }
  }
  __syncthreads();

  float f0[8], f1[8];
  {
    const float2 bb = *(const float2*)(bvo + 3 * 256 + d0);
    #pragma unroll
    for (int jj = 0; jj < 8; ++jj) { f0[jj] = bb.x; f1[jj] = bb.y; }
  }
  gemm16<64>(wagg4, (const uint4*)vo4 + (size_t)3 * 8192, h, tl, f0, f1);

  #pragma unroll
  for (int jj = 0; jj < 8; ++jj) {
    const int j = h * 8 + jj;
    const int g = v0 + j;
    const int vl = vlds[j];
    float2 r;
    r.x = vl ? f0[jj] : 0.f;
    r.y = vl ? f1[jj] : 0.f;
    *(float2*)(out + (size_t)g * CC + d0) = r;
  }
}

extern "C" void kernel_launch(void* const* d_in, const int* in_sizes, int n_in,
                              void* d_out, int out_size, void* d_ws, size_t ws_size,
                              hipStream_t stream) {
  const float* ptsf  = (const float*)d_in[0];
  const float* ptspe = (const float*)d_in[1];
  const float* knnf  = (const float*)d_in[2];
  const float* knnpe = (const float*)d_in[3];
  const float* sfeat = (const float*)d_in[4];
  const int*   maskp = (const int*)d_in[5];
  const float* Wq_t = (const float*)d_in[6];
  const float* Wk_t = (const float*)d_in[7];
  const float* Wv_t = (const float*)d_in[8];
  const float* Wo_t = (const float*)d_in[9];
  const float* bq_t = (const float*)d_in[10];
  const float* bk_t = (const float*)d_in[11];
  const float* bv_t = (const float*)d_in[12];
  const float* bo_t = (const float*)d_in[13];
  const float* Wq_c = (const float*)d_in[14];
  const float* Wk_c = (const float*)d_in[15];
  const float* Wv_c = (const float*)d_in[16];
  const float* Wo_c = (const float*)d_in[17];
  const float* bq_c = (const float*)d_in[18];
  const float* bk_c = (const float*)d_in[19];
  const float* bv_c = (const float*)d_in[20];
  const float* bo_c = (const float*)d_in[21];

  if (ws_size < WS_NEED_OLD) return;
  const int big = (ws_size >= WS_NEED_NEW) ? 1 : 0;

  char* ws = (char*)d_ws;
  __hip_bfloat16* qk4  = (__hip_bfloat16*)(ws + OFF_QK4);
  __hip_bfloat16* vo4  = (__hip_bfloat16*)(ws + OFF_VO4);
  __hip_bfloat16* vo4c = (__hip_bfloat16*)(ws + OFF_VO4C);
  float* WkT  = (float*)(ws + OFF_WKT);
  float* bqk  = (float*)(ws + OFF_BQK);
  float* bvo  = (float*)(ws + OFF_BVO);
  float* wqbk = (float*)(ws + OFF_WQBK);
  float* cqbk = (float*)(ws + OFF_CQBK);

  prep_transpose<<<256, 256, 0, stream>>>(Wk_t, Wk_c, WkT);
  prep_fold_vec<<<4, 256, 0, stream>>>(Wq_t, Wq_c, Wo_t, Wo_c,
                                       bq_t, bk_t, bv_t, bo_t,
                                       bq_c, bk_c, bv_c, bo_c,
                                       WkT, bqk, bvo, wqbk, cqbk);
  prep_fold_mm<<<2048, 256, 0, stream>>>(Wq_t, Wq_c, Wv_t, Wv_c, Wo_t, Wo_c,
                                         WkT, qk4, vo4, vo4c, big);
  if (big) {
    ushort* Ubf    = (ushort*)(ws + OFF_U);
    ushort* waggbf = (ushort*)(ws + OFF_WAGG);
    ushort* Ucbf   = (ushort*)(ws + OFF_UC);
    ushort* caggbf = (ushort*)(ws + OFF_CAGG);
    int*    validp = (int*)(ws + OFF_VALID);

    tproj_q<<<NBLK, 256, 0, stream>>>(ptsf, ptspe, (const ushort*)qk4, bqk, Ubf);
    score_t<<<dim3(NVOX / 4, SS), 256, 0, stream>>>(knnf, knnpe, Ubf, waggbf);
    tgemm_cd<<<NBLK, 256, 0, stream>>>(waggbf, (const ushort*)vo4,
                                       (const ushort*)qk4, bvo, bqk, Ucbf);
    score_c<<<NVOX / 4, 256, 0, stream>>>(sfeat, maskp, Ucbf, caggbf, validp);
    fgemm<<<NBLK, 256, 0, stream>>>(caggbf, (const ushort*)vo4c, bvo, validp,
                                    (float*)d_out);
  } else {
    stftr_main<<<NBLK, 256, 0, stream>>>(
        ptsf, ptspe, knnf, knnpe, sfeat, maskp,
        (const ushort*)qk4, (const ushort*)vo4, bqk, bvo, wqbk, cqbk,
        (float*)d_out);
  }
}

// Round 4
// 258.688 us; speedup vs baseline: 8.1160x; 1.7116x over previous
//
#include <hip/hip_runtime.h>
#include <math.h>

#define CC 256
#define KK 8
#define MM 6
#define SS 3
#define NVOX 12000
#define VB 16
#define NBLK (NVOX / VB)

typedef __attribute__((ext_vector_type(8))) short bf16x8;
typedef __attribute__((ext_vector_type(4))) float f32x4;

// ---- ws layout (bytes) ----
#define OFF_WKT    0u
#define OFF_WQKF   1048576u
#define OFF_WVOF   2097152u
#define OFF_WBIGF  3145728u
#define OFF_BQK    3932160u
#define OFF_BVO    3936256u
#define OFF_BBIG   3940352u
#define OFF_QK3PK  3941376u
#define OFF_WBIGPK 4334592u
#define OFF_WVOCPK 4727808u
#define OFF_U      4858880u
#define OFF_WAGG   23290880u
#define WS_NEED    41722880u

__device__ __forceinline__ float4 f4add(const float4 a, const float4 b) {
  return make_float4(a.x + b.x, a.y + b.y, a.z + b.z, a.w + b.w);
}
__device__ __forceinline__ float wred(float p) {
  #pragma unroll
  for (int off = 32; off; off >>= 1) p += __shfl_xor(p, off, 64);
  return p;
}
__device__ __forceinline__ uint f2bf(float x) {  // RNE to bf16 bits
  const uint u = __float_as_uint(x);
  return (u + 0x7fffu + ((u >> 16) & 1u)) >> 16;
}
__device__ __forceinline__ uint bfpack(float a, float b) {
  return (f2bf(b) << 16) | f2bf(a);
}
__device__ __forceinline__ float bflo(uint w) { return __uint_as_float(w << 16); }
__device__ __forceinline__ float bfhi(uint w) { return __uint_as_float(w & 0xffff0000u); }

__device__ __forceinline__ f32x4 mfma16(bf16x8 a, bf16x8 b, f32x4 c) {
  return __builtin_amdgcn_mfma_f32_16x16x32_bf16(a, b, c, 0, 0, 0);
}

// ---------------- prep kernels ----------------

__global__ __launch_bounds__(256) void prep_transpose(
    const float* __restrict__ Wk_t, const float* __restrict__ Wk_c,
    float* __restrict__ WkT) {
  __shared__ float tile[32][33];
  const int b = blockIdx.x;
  const int u = b >> 6, q = b & 63;
  const int ei0 = (q >> 3) * 32, dj0 = (q & 7) * 32;
  const float* src = (u < 3) ? (Wk_t + u * 65536) : Wk_c;
  const int tx = threadIdx.x & 31, ty = threadIdx.x >> 5;
  #pragma unroll
  for (int i = 0; i < 4; ++i) {
    const int le = ty + i * 8;
    tile[le][tx] = src[(ei0 + le) * 256 + dj0 + tx];
  }
  __syncthreads();
  #pragma unroll
  for (int i = 0; i < 4; ++i) {
    const int ld = ty + i * 8;
    WkT[u * 65536 + (dj0 + ld) * 256 + ei0 + tx] = tile[tx][ld];
  }
}

// Wqkf[u] = Wq_u @ WkT_u ; Wvof[u] = Wv_u @ Wo_u   (f32)
__global__ __launch_bounds__(256) void prep_fold_f32(
    const float* __restrict__ Wq_t, const float* __restrict__ Wq_c,
    const float* __restrict__ Wv_t, const float* __restrict__ Wv_c,
    const float* __restrict__ Wo_t, const float* __restrict__ Wo_c,
    const float* __restrict__ WkT,
    float* __restrict__ Wqkf, float* __restrict__ Wvof) {
  __shared__ float xrow[256];
  const int b = blockIdx.x;
  const int u = b >> 8, c = b & 255;
  const float *X, *Y; float* outp;
  if (u < 4) {
    X = (u < 3) ? (Wq_t + u * 65536) : Wq_c;
    Y = WkT + u * 65536;
    outp = Wqkf + u * 65536;
  } else {
    const int v = u - 4;
    X = (v < 3) ? (Wv_t + v * 65536) : Wv_c;
    Y = (v < 3) ? (Wo_t + v * 65536) : Wo_c;
    outp = Wvof + v * 65536;
  }
  const int t = threadIdx.x;
  xrow[t] = X[c * 256 + t];
  __syncthreads();
  float acc = 0.f;
  for (int d = 0; d < 256; ++d) acc += xrow[d] * Y[d * 256 + t];
  outp[c * 256 + t] = acc;
}

// bqk[u] = bq_u @ WkT_u ; bvo[u] = bv_u @ Wo_u + bo_u
__global__ __launch_bounds__(256) void prep_fold_vec2(
    const float* __restrict__ bq_t, const float* __restrict__ bq_c,
    const float* __restrict__ bv_t, const float* __restrict__ bv_c,
    const float* __restrict__ bo_t, const float* __restrict__ bo_c,
    const float* __restrict__ Wo_t, const float* __restrict__ Wo_c,
    const float* __restrict__ WkT,
    float* __restrict__ bqk, float* __restrict__ bvo) {
  const int u = blockIdx.x, t = threadIdx.x;
  const float* bq = (u < 3) ? bq_t + u * 256 : bq_c;
  const float* bv = (u < 3) ? bv_t + u * 256 : bv_c;
  const float* bo = (u < 3) ? bo_t + u * 256 : bo_c;
  const float* Wo = (u < 3) ? Wo_t + u * 65536 : Wo_c;
  const float* WT = WkT + u * 65536;
  float a1 = 0.f, a2 = 0.f;
  for (int d = 0; d < 256; ++d) {
    a1 += bq[d] * WT[d * 256 + t];
    a2 += bv[d] * Wo[d * 256 + t];
  }
  bqk[u * 256 + t] = a1;
  bvo[u * 256 + t] = a2 + bo[t];
}

// Wbigf[k][n] = sum_c Wvo_cat[k][c] * Wqkf3[c][n]   (k < 768)
__global__ __launch_bounds__(256) void prep_wbig(
    const float* __restrict__ Wvof, const float* __restrict__ Wqkf,
    float* __restrict__ Wbigf) {
  __shared__ float xrow[256];
  const int k = blockIdx.x;
  const int s = k >> 8, c = k & 255;
  const int t = threadIdx.x;
  xrow[t] = Wvof[s * 65536 + c * 256 + t];
  __syncthreads();
  const float* W3 = Wqkf + 3 * 65536;
  float acc = 0.f;
  for (int d = 0; d < 256; ++d) acc += xrow[d] * W3[d * 256 + t];
  Wbigf[k * 256 + t] = acc;
}

// bbig[n] = (sum_s bvo_s) @ Wqkf3 + bqk3
__global__ __launch_bounds__(256) void prep_bbig(
    const float* __restrict__ bvo, const float* __restrict__ bqk,
    const float* __restrict__ Wqkf, float* __restrict__ bbig) {
  __shared__ float bvs[256];
  const int t = threadIdx.x;
  bvs[t] = bvo[t] + bvo[256 + t] + bvo[512 + t];
  __syncthreads();
  const float* W3 = Wqkf + 3 * 65536;
  float acc = bqk[3 * 256 + t];
  for (int d = 0; d < 256; ++d) acc += bvs[d] * W3[d * 256 + t];
  bbig[t] = acc;
}

// pack B-operands into MFMA fragment order: uint4 = 8 bf16, k = kb*32+(lane>>4)*8+i, n = ng*16+(lane&15)
__global__ __launch_bounds__(256) void prep_pack(
    const float* __restrict__ Wqkf, const float* __restrict__ Wbigf,
    const float* __restrict__ Wvof,
    uint4* __restrict__ qk3pk, uint4* __restrict__ wbigpk,
    uint4* __restrict__ wvocpk) {
  const int gid = blockIdx.x * 256 + threadIdx.x;  // < 57344
  const float* src; uint4* dst;
  if (gid < 24576) {
    const int idx = gid;
    const int lane = idx & 63, kb = (idx >> 6) & 7, ng = idx >> 9;   // ng<48
    const int n = (ng & 15) * 16 + (lane & 15);
    const int k0 = kb * 32 + (lane >> 4) * 8;
    src = Wqkf + (ng >> 4) * 65536 + k0 * 256 + n;
    dst = qk3pk + idx;
  } else if (gid < 49152) {
    const int idx = gid - 24576;
    const int lane = idx & 63, kb = (idx >> 6) % 24, ng = idx / 1536; // ng<16, kb<24
    const int n = ng * 16 + (lane & 15);
    const int k0 = kb * 32 + (lane >> 4) * 8;
    src = Wbigf + k0 * 256 + n;
    dst = wbigpk + idx;
  } else {
    const int idx = gid - 49152;
    const int lane = idx & 63, kb = (idx >> 6) & 7, ng = idx >> 9;   // ng<16
    const int n = ng * 16 + (lane & 15);
    const int k0 = kb * 32 + (lane >> 4) * 8;
    src = Wvof + 3 * 65536 + k0 * 256 + n;
    dst = wvocpk + idx;
  }
  float f[8];
  #pragma unroll
  for (int i = 0; i < 8; ++i) f[i] = src[i * 256];
  uint4 o;
  o.x = bfpack(f[0], f[1]); o.y = bfpack(f[2], f[3]);
  o.z = bfpack(f[4], f[5]); o.w = bfpack(f[6], f[7]);
  *dst = o;
}

// ---------------- A: U = bf16(qb) @ Wqk3 + bqk  (MFMA, N=768) ----------------

__global__ __launch_bounds__(256) void tproj_mfma(
    const float* __restrict__ ptsf, const float* __restrict__ ptspe,
    const bf16x8* __restrict__ qk3pk, const float* __restrict__ bqk,
    uint* __restrict__ Ubf) {
  __shared__ char sh[33280];   // qbuf bf16[16][264] @0 ; Ustage bf16[16][776] @8448
  const int t = threadIdx.x, lane = t & 63, w = t >> 6;
  const int g0 = blockIdx.x * VB;
  uint* qb_u = (uint*)sh;
  {
    const float4* a4 = (const float4*)(ptsf + (size_t)g0 * CC);
    const float4* b4 = (const float4*)(ptspe + (size_t)g0 * CC);
    #pragma unroll
    for (int it = 0; it < 4; ++it) {
      const int idx = it * 256 + t;
      const int row = idx >> 6, c4 = idx & 63;
      const float4 va = a4[idx], vb = b4[idx];
      qb_u[row * 132 + c4 * 2]     = bfpack(va.x + vb.x, va.y + vb.y);
      qb_u[row * 132 + c4 * 2 + 1] = bfpack(va.z + vb.z, va.w + vb.w);
    }
  }
  __syncthreads();
  f32x4 acc[12];
  #pragma unroll
  for (int nb = 0; nb < 12; ++nb) acc[nb] = (f32x4){0.f, 0.f, 0.f, 0.f};
  const char* qbase = sh + (lane & 15) * 528 + (lane >> 4) * 16;
  #pragma unroll
  for (int kb = 0; kb < 8; ++kb) {
    const bf16x8 a = *(const bf16x8*)(qbase + kb * 64);
    #pragma unroll
    for (int nb = 0; nb < 12; ++nb) {
      const bf16x8 b = qk3pk[((w * 12 + nb) * 8 + kb) * 64 + lane];
      acc[nb] = mfma16(a, b, acc[nb]);
    }
  }
  ushort* us = (ushort*)(sh + 8448);
  #pragma unroll
  for (int nb = 0; nb < 12; ++nb) {
    const int n = (w * 12 + nb) * 16 + (lane & 15);
    const float bias = bqk[n];
    #pragma unroll
    for (int r = 0; r < 4; ++r) {
      const int row = (lane >> 4) * 4 + r;
      us[row * 776 + n] = (ushort)f2bf(acc[nb][r] + bias);
    }
  }
  __syncthreads();
  const uint* usu = (const uint*)(sh + 8448);
  #pragma unroll
  for (int it = 0; it < 24; ++it) {
    const int idx = it * 256 + t;
    const int u = idx & 127, rs = idx >> 7;
    const int s = rs % 3, row = rs / 3;
    Ubf[((size_t)s * NVOX + g0 + row) * 128 + u] = usu[row * 388 + s * 128 + u];
  }
}

// ---------------- B: temporal scores/softmax/aggregate (streaming) ----------------

__global__ __launch_bounds__(256) void score_t(
    const float* __restrict__ knnf, const float* __restrict__ knnpe,
    const ushort* __restrict__ Ubf, ushort* __restrict__ waggbf) {
  const int t = threadIdx.x, lane = t & 63, w = t >> 6;
  const int g = blockIdx.x * 4 + w;
  const int s = blockIdx.y;
  const size_t task = (size_t)s * NVOX + g;
  const float4* kfp = (const float4*)knnf;
  const float4* kpp = (const float4*)knnpe;
  const size_t rb = task * (KK * 64) + lane;
  float4 sm[KK];
  #pragma unroll
  for (int r = 0; r < KK; ++r) {
    const float4 kf = kfp[rb + r * 64];
    const float4 kp = kpp[rb + r * 64];
    sm[r] = f4add(kf, kp);
  }
  const uint2 uu = ((const uint2*)Ubf)[task * 64 + lane];
  const float4 u4 = make_float4(bflo(uu.x), bfhi(uu.x), bflo(uu.y), bfhi(uu.y));
  float sc[KK];
  #pragma unroll
  for (int r = 0; r < KK; ++r) {
    float p = sm[r].x * u4.x + sm[r].y * u4.y + sm[r].z * u4.z + sm[r].w * u4.w;
    sc[r] = wred(p) * 0.0625f;
  }
  float mx = sc[0];
  #pragma unroll
  for (int r = 1; r < KK; ++r) mx = fmaxf(mx, sc[r]);
  float e[KK], sum = 0.f;
  #pragma unroll
  for (int r = 0; r < KK; ++r) { e[r] = __expf(sc[r] - mx); sum += e[r]; }
  const float inv = 1.f / sum;
  float4 acc = make_float4(0.f, 0.f, 0.f, 0.f);
  #pragma unroll
  for (int r = 0; r < KK; ++r) {
    const float a = e[r] * inv;
    acc.x += a * sm[r].x; acc.y += a * sm[r].y;
    acc.z += a * sm[r].z; acc.w += a * sm[r].w;
  }
  uint2 o;
  o.x = bfpack(acc.x, acc.y);
  o.y = bfpack(acc.z, acc.w);
  ((uint2*)waggbf)[task * 64 + lane] = o;
}

// ---------------- CDEF fused: Uc MFMA -> cross softmax -> final MFMA -> store ----------------

__global__ __launch_bounds__(256) void cross_fused(
    const uint* __restrict__ waggbf, const float* __restrict__ sfeat,
    const int* __restrict__ maskp,
    const bf16x8* __restrict__ wbigpk, const bf16x8* __restrict__ wvocpk,
    const float* __restrict__ bbig, const float* __restrict__ bvoc,
    float* __restrict__ out) {
  // sh: Abuf bf16[16][776] @0 (24832) ; Ustage bf16[16][264] @24832 (8448)
  //     Cstage bf16[16][264] @0 (aliases dead Abuf) ; Ostage f32[16][260] @8448
  __shared__ char sh[33280];
  __shared__ int vlds[VB];
  const int t = threadIdx.x, lane = t & 63, w = t >> 6;
  const int g0 = blockIdx.x * VB;
  uint* ab_u = (uint*)sh;
  #pragma unroll
  for (int it = 0; it < 24; ++it) {
    const int idx = it * 256 + t;
    const int u = idx & 127, rs = idx >> 7;
    const int s = rs % 3, row = rs / 3;
    ab_u[row * 388 + s * 128 + u] = waggbf[((size_t)s * NVOX + g0 + row) * 128 + u];
  }
  __syncthreads();
  // phase 1: Uc = wagg_cat @ Wbig + bbig
  f32x4 acc[4];
  #pragma unroll
  for (int nb = 0; nb < 4; ++nb) acc[nb] = (f32x4){0.f, 0.f, 0.f, 0.f};
  {
    const char* abase = sh + (lane & 15) * 1552 + (lane >> 4) * 16;
    #pragma unroll 4
    for (int kb = 0; kb < 24; ++kb) {
      const bf16x8 a = *(const bf16x8*)(abase + kb * 64);
      #pragma unroll
      for (int nb = 0; nb < 4; ++nb) {
        const bf16x8 b = wbigpk[((w * 4 + nb) * 24 + kb) * 64 + lane];
        acc[nb] = mfma16(a, b, acc[nb]);
      }
    }
  }
  {
    ushort* ust = (ushort*)(sh + 24832);
    #pragma unroll
    for (int nb = 0; nb < 4; ++nb) {
      const int n = (w * 4 + nb) * 16 + (lane & 15);
      const float bias = bbig[n];
      #pragma unroll
      for (int r = 0; r < 4; ++r) {
        const int row = (lane >> 4) * 4 + r;
        ust[row * 264 + n] = (ushort)f2bf(acc[nb][r] + bias);
      }
    }
  }
  __syncthreads();
  // score phase (Abuf dead -> Cstage)
  {
    uint* cs_u = (uint*)sh;
    const uint* ust_u = (const uint*)(sh + 24832);
    const float4* sfp = (const float4*)sfeat;
    #pragma unroll
    for (int jj = 0; jj < 4; ++jj) {
      const int j = w * 4 + jj;
      const int g = g0 + j;
      const uint ua = ust_u[j * 132 + lane * 2];
      const uint ub = ust_u[j * 132 + lane * 2 + 1];
      const float4 u4 = make_float4(bflo(ua), bfhi(ua), bflo(ub), bfhi(ub));
      const size_t sb = (size_t)g * (MM * 64) + lane;
      float4 sf[MM]; float scm[MM]; int anyv = 0;
      #pragma unroll
      for (int m = 0; m < MM; ++m) {
        sf[m] = sfp[sb + m * 64];
        const int mk = maskp[(size_t)g * MM + m];
        anyv |= mk;
        float p = sf[m].x * u4.x + sf[m].y * u4.y + sf[m].z * u4.z + sf[m].w * u4.w;
        p = wred(p);
        scm[m] = mk ? p * 0.0625f : -1e9f;
      }
      float mx = scm[0];
      #pragma unroll
      for (int m = 1; m < MM; ++m) mx = fmaxf(mx, scm[m]);
      float e[MM], sum = 0.f;
      #pragma unroll
      for (int m = 0; m < MM; ++m) { e[m] = __expf(scm[m] - mx); sum += e[m]; }
      const float inv = 1.f / sum;
      float4 ag = make_float4(0.f, 0.f, 0.f, 0.f);
      #pragma unroll
      for (int m = 0; m < MM; ++m) {
        const float a = e[m] * inv;
        ag.x += a * sf[m].x; ag.y += a * sf[m].y;
        ag.z += a * sf[m].z; ag.w += a * sf[m].w;
      }
      cs_u[j * 132 + lane * 2]     = bfpack(ag.x, ag.y);
      cs_u[j * 132 + lane * 2 + 1] = bfpack(ag.z, ag.w);
      if (lane == 0) vlds[j] = anyv;
    }
  }
  __syncthreads();
  // F: out = cagg @ Wvo_c + bvoc
  f32x4 fac[4];
  #pragma unroll
  for (int nb = 0; nb < 4; ++nb) fac[nb] = (f32x4){0.f, 0.f, 0.f, 0.f};
  {
    const char* cbase = sh + (lane & 15) * 528 + (lane >> 4) * 16;
    #pragma unroll
    for (int kb = 0; kb < 8; ++kb) {
      const bf16x8 a = *(const bf16x8*)(cbase + kb * 64);
      #pragma unroll
      for (int nb = 0; nb < 4; ++nb) {
        const bf16x8 b = wvocpk[((w * 4 + nb) * 8 + kb) * 64 + lane];
        fac[nb] = mfma16(a, b, fac[nb]);
      }
    }
  }
  {
    float* ost = (float*)(sh + 8448);
    #pragma unroll
    for (int nb = 0; nb < 4; ++nb) {
      const int n = (w * 4 + nb) * 16 + (lane & 15);
      const float bias = bvoc[n];
      #pragma unroll
      for (int r = 0; r < 4; ++r) {
        const int row = (lane >> 4) * 4 + r;
        ost[row * 260 + n] = fac[nb][r] + bias;
      }
    }
  }
  __syncthreads();
  {
    const float* ost = (const float*)(sh + 8448);
    #pragma unroll
    for (int it = 0; it < 16; ++it) {
      const int idx = it * 256 + t;
      const int row = idx >> 8, d = idx & 255;
      out[((size_t)(g0 + row)) * 256 + d] = vlds[row] ? ost[row * 260 + d] : 0.f;
    }
  }
}

extern "C" void kernel_launch(void* const* d_in, const int* in_sizes, int n_in,
                              void* d_out, int out_size, void* d_ws, size_t ws_size,
                              hipStream_t stream) {
  const float* ptsf  = (const float*)d_in[0];
  const float* ptspe = (const float*)d_in[1];
  const float* knnf  = (const float*)d_in[2];
  const float* knnpe = (const float*)d_in[3];
  const float* sfeat = (const float*)d_in[4];
  const int*   maskp = (const int*)d_in[5];
  const float* Wq_t = (const float*)d_in[6];
  const float* Wk_t = (const float*)d_in[7];
  const float* Wv_t = (const float*)d_in[8];
  const float* Wo_t = (const float*)d_in[9];
  const float* bq_t = (const float*)d_in[10];
  const float* bk_t = (const float*)d_in[11];
  const float* bv_t = (const float*)d_in[12];
  const float* bo_t = (const float*)d_in[13];
  const float* Wq_c = (const float*)d_in[14];
  const float* Wk_c = (const float*)d_in[15];
  const float* Wv_c = (const float*)d_in[16];
  const float* Wo_c = (const float*)d_in[17];
  const float* bq_c = (const float*)d_in[18];
  const float* bk_c = (const float*)d_in[19];
  const float* bv_c = (const float*)d_in[20];
  const float* bo_c = (const float*)d_in[21];
  (void)bk_t; (void)bk_c;  // folded constants are softmax-invariant

  if (ws_size < WS_NEED) return;
  char* ws = (char*)d_ws;
  float* WkT    = (float*)(ws + OFF_WKT);
  float* Wqkf   = (float*)(ws + OFF_WQKF);
  float* Wvof   = (float*)(ws + OFF_WVOF);
  float* Wbigf  = (float*)(ws + OFF_WBIGF);
  float* bqk    = (float*)(ws + OFF_BQK);
  float* bvo    = (float*)(ws + OFF_BVO);
  float* bbig   = (float*)(ws + OFF_BBIG);
  uint4* qk3pk  = (uint4*)(ws + OFF_QK3PK);
  uint4* wbigpk = (uint4*)(ws + OFF_WBIGPK);
  uint4* wvocpk = (uint4*)(ws + OFF_WVOCPK);
  uint*  Ubf    = (uint*)(ws + OFF_U);
  ushort* waggbf = (ushort*)(ws + OFF_WAGG);

  prep_transpose<<<256, 256, 0, stream>>>(Wk_t, Wk_c, WkT);
  prep_fold_f32<<<2048, 256, 0, stream>>>(Wq_t, Wq_c, Wv_t, Wv_c, Wo_t, Wo_c,
                                          WkT, Wqkf, Wvof);
  prep_fold_vec2<<<4, 256, 0, stream>>>(bq_t, bq_c, bv_t, bv_c, bo_t, bo_c,
                                        Wo_t, Wo_c, WkT, bqk, bvo);
  prep_wbig<<<768, 256, 0, stream>>>(Wvof, Wqkf, Wbigf);
  prep_bbig<<<1, 256, 0, stream>>>(bvo, bqk, Wqkf, bbig);
  prep_pack<<<224, 256, 0, stream>>>(Wqkf, Wbigf, Wvof, qk3pk, wbigpk, wvocpk);

  tproj_mfma<<<NBLK, 256, 0, stream>>>(ptsf, ptspe, (const bf16x8*)qk3pk, bqk, Ubf);
  score_t<<<dim3(NVOX / 4, SS), 256, 0, stream>>>(knnf, knnpe, (const ushort*)Ubf,
                                                  waggbf);
  cross_fused<<<NBLK, 256, 0, stream>>>((const uint*)waggbf, sfeat, maskp,
                                        (const bf16x8*)wbigpk,
                                        (const bf16x8*)wvocpk,
                                        bbig, bvo + 3 * 256, (float*)d_out);
}

// Round 5
// 215.644 us; speedup vs baseline: 9.7360x; 1.1996x over previous
//
#include <hip/hip_runtime.h>
#include <math.h>

#define CC 256
#define KK 8
#define MM 6
#define SS 3
#define NVOX 12000
#define VB 16
#define NBLK (NVOX / VB)

typedef __attribute__((ext_vector_type(8))) short bf16x8;
typedef __attribute__((ext_vector_type(4))) float f32x4;
typedef __attribute__((ext_vector_type(4))) float fvec4;

// ---- ws layout (bytes) ----
#define OFF_WQKF3  0u           // f32 [256][256]  (cross Wqk, wbig B)
#define OFF_WVOF   262144u      // f32 [768][256]  (temporal Wvo concat, wbig A)
#define OFF_BQK    1048576u     // f32 [4][256]
#define OFF_BVO    1052672u     // f32 [4][256]
#define OFF_BBIG   1056768u     // f32 [256]
#define OFF_QK3PK  1057792u     // uint4 [48ng][8kb][64lane]
#define OFF_WBIGPK 1451008u     // uint4 [16ng][24kb][64lane]
#define OFF_WVOCPK 1844224u     // uint4 [16ng][8kb][64lane]
#define OFF_U      1975296u     // bf16 [3][12000][256]
#define OFF_WAGG   20407296u    // bf16 [3][12000][256]
#define WS_NEED    38839296u

__device__ __forceinline__ float wred(float p) {
  #pragma unroll
  for (int off = 32; off; off >>= 1) p += __shfl_xor(p, off, 64);
  return p;
}
__device__ __forceinline__ uint f2bf(float x) {  // RNE to bf16 bits
  const uint u = __float_as_uint(x);
  return (u + 0x7fffu + ((u >> 16) & 1u)) >> 16;
}
__device__ __forceinline__ uint bfpack(float a, float b) {
  return (f2bf(b) << 16) | f2bf(a);
}
__device__ __forceinline__ float bflo(uint w) { return __uint_as_float(w << 16); }
__device__ __forceinline__ float bfhi(uint w) { return __uint_as_float(w & 0xffff0000u); }

__device__ __forceinline__ f32x4 mfma16(bf16x8 a, bf16x8 b, f32x4 c) {
  return __builtin_amdgcn_mfma_f32_16x16x32_bf16(a, b, c, 0, 0, 0);
}

// ---------------- prep kernel 1: all 8 folds + bias folds ----------------
// blocks 0..255: matrix u = b>>5 (0..3: Wqk_u = Wq_u @ Wk_u^T ; 4..7: Wvo_v = Wv_v @ Wo_v),
//                rows c0..c0+7 where c0 = (b&31)*8. Emits packed fragments directly
//                for u=0..2 (qk3pk) and u=7 (wvocpk); f32 for u=3 (Wqkf3), u=4..6 (Wvof).
// blocks 256..259: bias folds bqk[u], bvo[u].
__global__ __launch_bounds__(256) void prep_fold_all(
    const float* __restrict__ Wq_t, const float* __restrict__ Wq_c,
    const float* __restrict__ Wk_t, const float* __restrict__ Wk_c,
    const float* __restrict__ Wv_t, const float* __restrict__ Wv_c,
    const float* __restrict__ Wo_t, const float* __restrict__ Wo_c,
    const float* __restrict__ bq_t, const float* __restrict__ bq_c,
    const float* __restrict__ bv_t, const float* __restrict__ bv_c,
    const float* __restrict__ bo_t, const float* __restrict__ bo_c,
    float* __restrict__ Wqkf3, float* __restrict__ Wvof,
    float* __restrict__ bqk, float* __restrict__ bvo,
    uint4* __restrict__ qk3pk, uint4* __restrict__ wvocpk) {
  const int b = blockIdx.x, t = threadIdx.x;
  if (b < 256) {
    const int u = b >> 5, c0 = (b & 31) * 8;
    __shared__ float xl[8][256];
    const float* X;
    if (u < 4) X = (u < 3) ? (Wq_t + u * 65536) : Wq_c;
    else { const int v = u - 4; X = (v < 3) ? (Wv_t + v * 65536) : Wv_c; }
    #pragma unroll
    for (int i = 0; i < 8; ++i) xl[i][t] = X[(c0 + i) * 256 + t];
    __syncthreads();
    float acc[8] = {0.f, 0.f, 0.f, 0.f, 0.f, 0.f, 0.f, 0.f};
    if (u < 4) {
      // NT: out[c][t] = sum_d X[c][d] * Wk[t][d]  (thread streams own Wk row)
      const float* Wk = (u < 3) ? (Wk_t + u * 65536) : Wk_c;
      const float4* wr = (const float4*)(Wk + t * 256);
      #pragma unroll 4
      for (int d4 = 0; d4 < 64; ++d4) {
        const float4 wv = wr[d4];
        #pragma unroll
        for (int j = 0; j < 8; ++j) {
          acc[j] += xl[j][d4 * 4] * wv.x + xl[j][d4 * 4 + 1] * wv.y +
                    xl[j][d4 * 4 + 2] * wv.z + xl[j][d4 * 4 + 3] * wv.w;
        }
      }
    } else {
      // NN: out[c][t] = sum_d X[c][d] * Wo[d][t]  (coalesced column access)
      const int v = u - 4;
      const float* Wo = (v < 3) ? (Wo_t + v * 65536) : Wo_c;
      #pragma unroll 4
      for (int d = 0; d < 256; ++d) {
        const float w = Wo[d * 256 + t];
        #pragma unroll
        for (int j = 0; j < 8; ++j) acc[j] += xl[j][d] * w;
      }
    }
    const int lane = (((c0 >> 3) & 3) << 4) | (t & 15);
    if (u < 3) {
      uint4 o;
      o.x = bfpack(acc[0], acc[1]); o.y = bfpack(acc[2], acc[3]);
      o.z = bfpack(acc[4], acc[5]); o.w = bfpack(acc[6], acc[7]);
      qk3pk[((u * 16 + (t >> 4)) * 8 + (c0 >> 5)) * 64 + lane] = o;
    } else if (u == 3) {
      #pragma unroll
      for (int j = 0; j < 8; ++j) Wqkf3[(c0 + j) * 256 + t] = acc[j];
    } else if (u < 7) {
      const int v = u - 4;
      #pragma unroll
      for (int j = 0; j < 8; ++j) Wvof[(v * 256 + c0 + j) * 256 + t] = acc[j];
    } else {
      uint4 o;
      o.x = bfpack(acc[0], acc[1]); o.y = bfpack(acc[2], acc[3]);
      o.z = bfpack(acc[4], acc[5]); o.w = bfpack(acc[6], acc[7]);
      wvocpk[((t >> 4) * 8 + (c0 >> 5)) * 64 + lane] = o;
    }
  } else {
    const int u = b - 256;
    __shared__ float bql[256], bvl[256];
    const float* bq = (u < 3) ? (bq_t + u * 256) : bq_c;
    const float* bv = (u < 3) ? (bv_t + u * 256) : bv_c;
    const float* bo = (u < 3) ? (bo_t + u * 256) : bo_c;
    bql[t] = bq[t]; bvl[t] = bv[t];
    __syncthreads();
    const float* Wk = (u < 3) ? (Wk_t + u * 65536) : Wk_c;
    const float* Wo = (u < 3) ? (Wo_t + u * 65536) : Wo_c;
    const float4* wr = (const float4*)(Wk + t * 256);
    float a1 = 0.f, a2 = 0.f;
    #pragma unroll 4
    for (int d4 = 0; d4 < 64; ++d4) {
      const float4 wv = wr[d4];
      a1 += bql[d4 * 4] * wv.x + bql[d4 * 4 + 1] * wv.y +
            bql[d4 * 4 + 2] * wv.z + bql[d4 * 4 + 3] * wv.w;
    }
    #pragma unroll 4
    for (int d = 0; d < 256; ++d) a2 += bvl[d] * Wo[d * 256 + t];
    bqk[u * 256 + t] = a1;
    bvo[u * 256 + t] = a2 + bo[t];
  }
}

// ---------------- prep kernel 2: Wbig = Wvo_cat @ Wqk_c (packed) + bbig ----------------
__global__ __launch_bounds__(256) void prep_wbig2(
    const float* __restrict__ Wvof, const float* __restrict__ Wqkf3,
    const float* __restrict__ bqk, const float* __restrict__ bvo,
    uint4* __restrict__ wbigpk, float* __restrict__ bbig) {
  const int b = blockIdx.x, t = threadIdx.x;
  if (b < 96) {
    const int c0 = b * 8;
    __shared__ float xl[8][256];
    #pragma unroll
    for (int i = 0; i < 8; ++i) xl[i][t] = Wvof[(c0 + i) * 256 + t];
    __syncthreads();
    float acc[8] = {0.f, 0.f, 0.f, 0.f, 0.f, 0.f, 0.f, 0.f};
    #pragma unroll 4
    for (int d = 0; d < 256; ++d) {
      const float w = Wqkf3[d * 256 + t];
      #pragma unroll
      for (int j = 0; j < 8; ++j) acc[j] += xl[j][d] * w;
    }
    uint4 o;
    o.x = bfpack(acc[0], acc[1]); o.y = bfpack(acc[2], acc[3]);
    o.z = bfpack(acc[4], acc[5]); o.w = bfpack(acc[6], acc[7]);
    const int lane = (((c0 >> 3) & 3) << 4) | (t & 15);
    wbigpk[((t >> 4) * 24 + (c0 >> 5)) * 64 + lane] = o;
  } else {
    __shared__ float bvs[256];
    bvs[t] = bvo[t] + bvo[256 + t] + bvo[512 + t];
    __syncthreads();
    float acc = bqk[3 * 256 + t];
    #pragma unroll 4
    for (int d = 0; d < 256; ++d) acc += bvs[d] * Wqkf3[d * 256 + t];
    bbig[t] = acc;
  }
}

// ---------------- A: U = bf16(qb) @ Wqk3 + bqk  (MFMA, N=768) ----------------

__global__ __launch_bounds__(256) void tproj_mfma(
    const float* __restrict__ ptsf, const float* __restrict__ ptspe,
    const bf16x8* __restrict__ qk3pk, const float* __restrict__ bqk,
    uint* __restrict__ Ubf) {
  __shared__ char sh[33280];   // qbuf bf16[16][264] @0 ; Ustage bf16[16][776] @8448
  const int t = threadIdx.x, lane = t & 63, w = t >> 6;
  const int g0 = blockIdx.x * VB;
  uint* qb_u = (uint*)sh;
  {
    const float4* a4 = (const float4*)(ptsf + (size_t)g0 * CC);
    const float4* b4 = (const float4*)(ptspe + (size_t)g0 * CC);
    #pragma unroll
    for (int it = 0; it < 4; ++it) {
      const int idx = it * 256 + t;
      const int row = idx >> 6, c4 = idx & 63;
      const float4 va = a4[idx], vb = b4[idx];
      qb_u[row * 132 + c4 * 2]     = bfpack(va.x + vb.x, va.y + vb.y);
      qb_u[row * 132 + c4 * 2 + 1] = bfpack(va.z + vb.z, va.w + vb.w);
    }
  }
  __syncthreads();
  f32x4 acc[12];
  #pragma unroll
  for (int nb = 0; nb < 12; ++nb) acc[nb] = (f32x4){0.f, 0.f, 0.f, 0.f};
  const char* qbase = sh + (lane & 15) * 528 + (lane >> 4) * 16;
  #pragma unroll
  for (int kb = 0; kb < 8; ++kb) {
    const bf16x8 a = *(const bf16x8*)(qbase + kb * 64);
    #pragma unroll
    for (int nb = 0; nb < 12; ++nb) {
      const bf16x8 bb = qk3pk[((w * 12 + nb) * 8 + kb) * 64 + lane];
      acc[nb] = mfma16(a, bb, acc[nb]);
    }
  }
  ushort* us = (ushort*)(sh + 8448);
  #pragma unroll
  for (int nb = 0; nb < 12; ++nb) {
    const int n = (w * 12 + nb) * 16 + (lane & 15);
    const float bias = bqk[n];
    #pragma unroll
    for (int r = 0; r < 4; ++r) {
      const int row = (lane >> 4) * 4 + r;
      us[row * 776 + n] = (ushort)f2bf(acc[nb][r] + bias);
    }
  }
  __syncthreads();
  const uint* usu = (const uint*)(sh + 8448);
  #pragma unroll
  for (int it = 0; it < 24; ++it) {
    const int idx = it * 256 + t;
    const int u = idx & 127, rs = idx >> 7;
    const int s = rs % 3, row = rs / 3;
    Ubf[((size_t)s * NVOX + g0 + row) * 128 + u] = usu[row * 388 + s * 128 + u];
  }
}

// ---------------- B: temporal scores/softmax/aggregate (streaming) ----------------

__global__ __launch_bounds__(256) void score_t(
    const float* __restrict__ knnf, const float* __restrict__ knnpe,
    const ushort* __restrict__ Ubf, ushort* __restrict__ waggbf) {
  const int t = threadIdx.x, lane = t & 63, w = t >> 6;
  const int g = blockIdx.x * 4 + w;
  const int s = blockIdx.y;
  const size_t task = (size_t)s * NVOX + g;
  const fvec4* kfp = (const fvec4*)knnf;
  const fvec4* kpp = (const fvec4*)knnpe;
  const size_t rb = task * (KK * 64) + lane;
  fvec4 sm[KK];
  #pragma unroll
  for (int r = 0; r < KK; ++r) {
    const fvec4 kf = __builtin_nontemporal_load(&kfp[rb + r * 64]);
    const fvec4 kp = __builtin_nontemporal_load(&kpp[rb + r * 64]);
    sm[r] = kf + kp;
  }
  const uint2 uu = ((const uint2*)Ubf)[task * 64 + lane];
  const float u0 = bflo(uu.x), u1 = bfhi(uu.x), u2 = bflo(uu.y), u3 = bfhi(uu.y);
  float sc[KK];
  #pragma unroll
  for (int r = 0; r < KK; ++r) {
    float p = sm[r].x * u0 + sm[r].y * u1 + sm[r].z * u2 + sm[r].w * u3;
    sc[r] = wred(p) * 0.0625f;
  }
  float mx = sc[0];
  #pragma unroll
  for (int r = 1; r < KK; ++r) mx = fmaxf(mx, sc[r]);
  float e[KK], sum = 0.f;
  #pragma unroll
  for (int r = 0; r < KK; ++r) { e[r] = __expf(sc[r] - mx); sum += e[r]; }
  const float inv = 1.f / sum;
  fvec4 acc = (fvec4){0.f, 0.f, 0.f, 0.f};
  #pragma unroll
  for (int r = 0; r < KK; ++r) acc += (e[r] * inv) * sm[r];
  uint2 o;
  o.x = bfpack(acc.x, acc.y);
  o.y = bfpack(acc.z, acc.w);
  ((uint2*)waggbf)[task * 64 + lane] = o;
}

// ---------------- CDEF fused: Uc MFMA -> cross softmax -> final MFMA -> store ----------------

__global__ __launch_bounds__(256) void cross_fused(
    const uint* __restrict__ waggbf, const float* __restrict__ sfeat,
    const int* __restrict__ maskp,
    const bf16x8* __restrict__ wbigpk, const bf16x8* __restrict__ wvocpk,
    const float* __restrict__ bbig, const float* __restrict__ bvoc,
    float* __restrict__ out) {
  __shared__ char sh[33280];
  __shared__ int vlds[VB];
  const int t = threadIdx.x, lane = t & 63, w = t >> 6;
  const int g0 = blockIdx.x * VB;
  uint* ab_u = (uint*)sh;
  #pragma unroll
  for (int it = 0; it < 24; ++it) {
    const int idx = it * 256 + t;
    const int u = idx & 127, rs = idx >> 7;
    const int s = rs % 3, row = rs / 3;
    ab_u[row * 388 + s * 128 + u] = waggbf[((size_t)s * NVOX + g0 + row) * 128 + u];
  }
  __syncthreads();
  // phase 1: Uc = wagg_cat @ Wbig + bbig
  f32x4 acc[4];
  #pragma unroll
  for (int nb = 0; nb < 4; ++nb) acc[nb] = (f32x4){0.f, 0.f, 0.f, 0.f};
  {
    const char* abase = sh + (lane & 15) * 1552 + (lane >> 4) * 16;
    #pragma unroll 4
    for (int kb = 0; kb < 24; ++kb) {
      const bf16x8 a = *(const bf16x8*)(abase + kb * 64);
      #pragma unroll
      for (int nb = 0; nb < 4; ++nb) {
        const bf16x8 bb = wbigpk[((w * 4 + nb) * 24 + kb) * 64 + lane];
        acc[nb] = mfma16(a, bb, acc[nb]);
      }
    }
  }
  {
    ushort* ust = (ushort*)(sh + 24832);
    #pragma unroll
    for (int nb = 0; nb < 4; ++nb) {
      const int n = (w * 4 + nb) * 16 + (lane & 15);
      const float bias = bbig[n];
      #pragma unroll
      for (int r = 0; r < 4; ++r) {
        const int row = (lane >> 4) * 4 + r;
        ust[row * 264 + n] = (ushort)f2bf(acc[nb][r] + bias);
      }
    }
  }
  __syncthreads();
  // score phase (Abuf dead -> Cstage)
  {
    uint* cs_u = (uint*)sh;
    const uint* ust_u = (const uint*)(sh + 24832);
    const float4* sfp = (const float4*)sfeat;
    #pragma unroll
    for (int jj = 0; jj < 4; ++jj) {
      const int j = w * 4 + jj;
      const int g = g0 + j;
      const uint ua = ust_u[j * 132 + lane * 2];
      const uint ub = ust_u[j * 132 + lane * 2 + 1];
      const float u0 = bflo(ua), u1 = bfhi(ua), u2 = bflo(ub), u3 = bfhi(ub);
      const size_t sb = (size_t)g * (MM * 64) + lane;
      float4 sf[MM]; float scm[MM]; int anyv = 0;
      #pragma unroll
      for (int m = 0; m < MM; ++m) {
        sf[m] = sfp[sb + m * 64];
        const int mk = maskp[(size_t)g * MM + m];
        anyv |= mk;
        float p = sf[m].x * u0 + sf[m].y * u1 + sf[m].z * u2 + sf[m].w * u3;
        p = wred(p);
        scm[m] = mk ? p * 0.0625f : -1e9f;
      }
      float mx = scm[0];
      #pragma unroll
      for (int m = 1; m < MM; ++m) mx = fmaxf(mx, scm[m]);
      float e[MM], sum = 0.f;
      #pragma unroll
      for (int m = 0; m < MM; ++m) { e[m] = __expf(scm[m] - mx); sum += e[m]; }
      const float inv = 1.f / sum;
      float4 ag = make_float4(0.f, 0.f, 0.f, 0.f);
      #pragma unroll
      for (int m = 0; m < MM; ++m) {
        const float a = e[m] * inv;
        ag.x += a * sf[m].x; ag.y += a * sf[m].y;
        ag.z += a * sf[m].z; ag.w += a * sf[m].w;
      }
      cs_u[j * 132 + lane * 2]     = bfpack(ag.x, ag.y);
      cs_u[j * 132 + lane * 2 + 1] = bfpack(ag.z, ag.w);
      if (lane == 0) vlds[j] = anyv;
    }
  }
  __syncthreads();
  // F: out = cagg @ Wvo_c + bvoc
  f32x4 fac[4];
  #pragma unroll
  for (int nb = 0; nb < 4; ++nb) fac[nb] = (f32x4){0.f, 0.f, 0.f, 0.f};
  {
    const char* cbase = sh + (lane & 15) * 528 + (lane >> 4) * 16;
    #pragma unroll
    for (int kb = 0; kb < 8; ++kb) {
      const bf16x8 a = *(const bf16x8*)(cbase + kb * 64);
      #pragma unroll
      for (int nb = 0; nb < 4; ++nb) {
        const bf16x8 bb = wvocpk[((w * 4 + nb) * 8 + kb) * 64 + lane];
        fac[nb] = mfma16(a, bb, fac[nb]);
      }
    }
  }
  {
    float* ost = (float*)(sh + 8448);
    #pragma unroll
    for (int nb = 0; nb < 4; ++nb) {
      const int n = (w * 4 + nb) * 16 + (lane & 15);
      const float bias = bvoc[n];
      #pragma unroll
      for (int r = 0; r < 4; ++r) {
        const int row = (lane >> 4) * 4 + r;
        ost[row * 260 + n] = fac[nb][r] + bias;
      }
    }
  }
  __syncthreads();
  {
    const float* ost = (const float*)(sh + 8448);
    #pragma unroll
    for (int it = 0; it < 16; ++it) {
      const int idx = it * 256 + t;
      const int row = idx >> 8, d = idx & 255;
      out[((size_t)(g0 + row)) * 256 + d] = vlds[row] ? ost[row * 260 + d] : 0.f;
    }
  }
}

extern "C" void kernel_launch(void* const* d_in, const int* in_sizes, int n_in,
                              void* d_out, int out_size, void* d_ws, size_t ws_size,
                              hipStream_t stream) {
  const float* ptsf  = (const float*)d_in[0];
  const float* ptspe = (const float*)d_in[1];
  const float* knnf  = (const float*)d_in[2];
  const float* knnpe = (const float*)d_in[3];
  const float* sfeat = (const float*)d_in[4];
  const int*   maskp = (const int*)d_in[5];
  const float* Wq_t = (const float*)d_in[6];
  const float* Wk_t = (const float*)d_in[7];
  const float* Wv_t = (const float*)d_in[8];
  const float* Wo_t = (const float*)d_in[9];
  const float* bq_t = (const float*)d_in[10];
  const float* bk_t = (const float*)d_in[11];
  const float* bv_t = (const float*)d_in[12];
  const float* bo_t = (const float*)d_in[13];
  const float* Wq_c = (const float*)d_in[14];
  const float* Wk_c = (const float*)d_in[15];
  const float* Wv_c = (const float*)d_in[16];
  const float* Wo_c = (const float*)d_in[17];
  const float* bq_c = (const float*)d_in[18];
  const float* bk_c = (const float*)d_in[19];
  const float* bv_c = (const float*)d_in[20];
  const float* bo_c = (const float*)d_in[21];
  (void)bk_t; (void)bk_c;  // folded score constants are softmax-shift-invariant

  if (ws_size < WS_NEED) return;
  char* ws = (char*)d_ws;
  float* Wqkf3  = (float*)(ws + OFF_WQKF3);
  float* Wvof   = (float*)(ws + OFF_WVOF);
  float* bqk    = (float*)(ws + OFF_BQK);
  float* bvo    = (float*)(ws + OFF_BVO);
  float* bbig   = (float*)(ws + OFF_BBIG);
  uint4* qk3pk  = (uint4*)(ws + OFF_QK3PK);
  uint4* wbigpk = (uint4*)(ws + OFF_WBIGPK);
  uint4* wvocpk = (uint4*)(ws + OFF_WVOCPK);
  uint*  Ubf    = (uint*)(ws + OFF_U);
  ushort* waggbf = (ushort*)(ws + OFF_WAGG);

  prep_fold_all<<<260, 256, 0, stream>>>(
      Wq_t, Wq_c, Wk_t, Wk_c, Wv_t, Wv_c, Wo_t, Wo_c,
      bq_t, bq_c, bv_t, bv_c, bo_t, bo_c,
      Wqkf3, Wvof, bqk, bvo, qk3pk, wvocpk);
  prep_wbig2<<<97, 256, 0, stream>>>(Wvof, Wqkf3, bqk, bvo, wbigpk, bbig);

  tproj_mfma<<<NBLK, 256, 0, stream>>>(ptsf, ptspe, (const bf16x8*)qk3pk, bqk, Ubf);
  score_t<<<dim3(NVOX / 4, SS), 256, 0, stream>>>(knnf, knnpe, (const ushort*)Ubf,
                                                  (ushort*)waggbf);
  cross_fused<<<NBLK, 256, 0, stream>>>((const uint*)waggbf, sfeat, maskp,
                                        (const bf16x8*)wbigpk,
                                        (const bf16x8*)wvocpk,
                                        bbig, bvo + 3 * 256, (float*)d_out);
}

// Round 6
// 171.208 us; speedup vs baseline: 12.2629x; 1.2595x over previous
//
#include <hip/hip_runtime.h>
#include <math.h>

#define CC 256
#define KK 8
#define MM 6
#define SS 3
#define NVOX 12000
#define VB 16
#define NBLK (NVOX / VB)

typedef __attribute__((ext_vector_type(8))) short bf16x8;
typedef __attribute__((ext_vector_type(4))) float f32x4;
typedef __attribute__((ext_vector_type(4))) float fvec4;

// ---- ws layout (bytes) ----
#define OFF_WQKF3  0u           // f32 [256][256]  (cross Wqk, wbig B)
#define OFF_WVOF   262144u      // f32 [768][256]  (temporal Wvo concat, wbig A)
#define OFF_BQK    1048576u     // f32 [4][256]
#define OFF_BVO    1052672u     // f32 [4][256]
#define OFF_BBIG   1056768u     // f32 [256]
#define OFF_QK3PK  1057792u     // uint4 [48ng][8kb][64lane]
#define OFF_WBIGPK 1451008u     // uint4 [16ng][24kb][64lane]
#define OFF_WVOCPK 1844224u     // uint4 [16ng][8kb][64lane]
#define WS_NEED    1975296u

__device__ __forceinline__ float wred(float p) {
  #pragma unroll
  for (int off = 32; off; off >>= 1) p += __shfl_xor(p, off, 64);
  return p;
}
__device__ __forceinline__ uint f2bf(float x) {  // RNE to bf16 bits
  const uint u = __float_as_uint(x);
  return (u + 0x7fffu + ((u >> 16) & 1u)) >> 16;
}
__device__ __forceinline__ uint bfpack(float a, float b) {
  return (f2bf(b) << 16) | f2bf(a);
}
__device__ __forceinline__ float bflo(uint w) { return __uint_as_float(w << 16); }
__device__ __forceinline__ float bfhi(uint w) { return __uint_as_float(w & 0xffff0000u); }

__device__ __forceinline__ f32x4 mfma16(bf16x8 a, bf16x8 b, f32x4 c) {
  return __builtin_amdgcn_mfma_f32_16x16x32_bf16(a, b, c, 0, 0, 0);
}

// ---------------- prep kernel 1: all 8 folds + bias folds ----------------
__global__ __launch_bounds__(256) void prep_fold_all(
    const float* __restrict__ Wq_t, const float* __restrict__ Wq_c,
    const float* __restrict__ Wk_t, const float* __restrict__ Wk_c,
    const float* __restrict__ Wv_t, const float* __restrict__ Wv_c,
    const float* __restrict__ Wo_t, const float* __restrict__ Wo_c,
    const float* __restrict__ bq_t, const float* __restrict__ bq_c,
    const float* __restrict__ bv_t, const float* __restrict__ bv_c,
    const float* __restrict__ bo_t, const float* __restrict__ bo_c,
    float* __restrict__ Wqkf3, float* __restrict__ Wvof,
    float* __restrict__ bqk, float* __restrict__ bvo,
    uint4* __restrict__ qk3pk, uint4* __restrict__ wvocpk) {
  const int b = blockIdx.x, t = threadIdx.x;
  if (b < 256) {
    const int u = b >> 5, c0 = (b & 31) * 8;
    __shared__ float xl[8][256];
    const float* X;
    if (u < 4) X = (u < 3) ? (Wq_t + u * 65536) : Wq_c;
    else { const int v = u - 4; X = (v < 3) ? (Wv_t + v * 65536) : Wv_c; }
    #pragma unroll
    for (int i = 0; i < 8; ++i) xl[i][t] = X[(c0 + i) * 256 + t];
    __syncthreads();
    float acc[8] = {0.f, 0.f, 0.f, 0.f, 0.f, 0.f, 0.f, 0.f};
    if (u < 4) {
      const float* Wk = (u < 3) ? (Wk_t + u * 65536) : Wk_c;
      const float4* wr = (const float4*)(Wk + t * 256);
      #pragma unroll 4
      for (int d4 = 0; d4 < 64; ++d4) {
        const float4 wv = wr[d4];
        #pragma unroll
        for (int j = 0; j < 8; ++j) {
          acc[j] += xl[j][d4 * 4] * wv.x + xl[j][d4 * 4 + 1] * wv.y +
                    xl[j][d4 * 4 + 2] * wv.z + xl[j][d4 * 4 + 3] * wv.w;
        }
      }
    } else {
      const int v = u - 4;
      const float* Wo = (v < 3) ? (Wo_t + v * 65536) : Wo_c;
      #pragma unroll 4
      for (int d = 0; d < 256; ++d) {
        const float w = Wo[d * 256 + t];
        #pragma unroll
        for (int j = 0; j < 8; ++j) acc[j] += xl[j][d] * w;
      }
    }
    const int lane = (((c0 >> 3) & 3) << 4) | (t & 15);
    if (u < 3) {
      uint4 o;
      o.x = bfpack(acc[0], acc[1]); o.y = bfpack(acc[2], acc[3]);
      o.z = bfpack(acc[4], acc[5]); o.w = bfpack(acc[6], acc[7]);
      qk3pk[((u * 16 + (t >> 4)) * 8 + (c0 >> 5)) * 64 + lane] = o;
    } else if (u == 3) {
      #pragma unroll
      for (int j = 0; j < 8; ++j) Wqkf3[(c0 + j) * 256 + t] = acc[j];
    } else if (u < 7) {
      const int v = u - 4;
      #pragma unroll
      for (int j = 0; j < 8; ++j) Wvof[(v * 256 + c0 + j) * 256 + t] = acc[j];
    } else {
      uint4 o;
      o.x = bfpack(acc[0], acc[1]); o.y = bfpack(acc[2], acc[3]);
      o.z = bfpack(acc[4], acc[5]); o.w = bfpack(acc[6], acc[7]);
      wvocpk[((t >> 4) * 8 + (c0 >> 5)) * 64 + lane] = o;
    }
  } else {
    const int u = b - 256;
    __shared__ float bql[256], bvl[256];
    const float* bq = (u < 3) ? (bq_t + u * 256) : bq_c;
    const float* bv = (u < 3) ? (bv_t + u * 256) : bv_c;
    const float* bo = (u < 3) ? (bo_t + u * 256) : bo_c;
    bql[t] = bq[t]; bvl[t] = bv[t];
    __syncthreads();
    const float* Wk = (u < 3) ? (Wk_t + u * 65536) : Wk_c;
    const float* Wo = (u < 3) ? (Wo_t + u * 65536) : Wo_c;
    const float4* wr = (const float4*)(Wk + t * 256);
    float a1 = 0.f, a2 = 0.f;
    #pragma unroll 4
    for (int d4 = 0; d4 < 64; ++d4) {
      const float4 wv = wr[d4];
      a1 += bql[d4 * 4] * wv.x + bql[d4 * 4 + 1] * wv.y +
            bql[d4 * 4 + 2] * wv.z + bql[d4 * 4 + 3] * wv.w;
    }
    #pragma unroll 4
    for (int d = 0; d < 256; ++d) a2 += bvl[d] * Wo[d * 256 + t];
    bqk[u * 256 + t] = a1;
    bvo[u * 256 + t] = a2 + bo[t];
  }
}

// ---------------- prep kernel 2: Wbig = Wvo_cat @ Wqk_c (packed) + bbig ----------------
__global__ __launch_bounds__(256) void prep_wbig2(
    const float* __restrict__ Wvof, const float* __restrict__ Wqkf3,
    const float* __restrict__ bqk, const float* __restrict__ bvo,
    uint4* __restrict__ wbigpk, float* __restrict__ bbig) {
  const int b = blockIdx.x, t = threadIdx.x;
  if (b < 96) {
    const int c0 = b * 8;
    __shared__ float xl[8][256];
    #pragma unroll
    for (int i = 0; i < 8; ++i) xl[i][t] = Wvof[(c0 + i) * 256 + t];
    __syncthreads();
    float acc[8] = {0.f, 0.f, 0.f, 0.f, 0.f, 0.f, 0.f, 0.f};
    #pragma unroll 4
    for (int d = 0; d < 256; ++d) {
      const float w = Wqkf3[d * 256 + t];
      #pragma unroll
      for (int j = 0; j < 8; ++j) acc[j] += xl[j][d] * w;
    }
    uint4 o;
    o.x = bfpack(acc[0], acc[1]); o.y = bfpack(acc[2], acc[3]);
    o.z = bfpack(acc[4], acc[5]); o.w = bfpack(acc[6], acc[7]);
    const int lane = (((c0 >> 3) & 3) << 4) | (t & 15);
    wbigpk[((t >> 4) * 24 + (c0 >> 5)) * 64 + lane] = o;
  } else {
    __shared__ float bvs[256];
    bvs[t] = bvo[t] + bvo[256 + t] + bvo[512 + t];
    __syncthreads();
    float acc = bqk[3 * 256 + t];
    #pragma unroll 4
    for (int d = 0; d < 256; ++d) acc += bvs[d] * Wqkf3[d * 256 + t];
    bbig[t] = acc;
  }
}

// ---------------- mega kernel: whole per-voxel pipeline, intermediates in LDS ----------------
// shA: U bf16[16][776] (ph1->ph2) / Uc bf16[16][264] (ph3->ph4) / Ost f32[16][260]@8448 (ph5)
// shB: qb bf16[16][264] (ph1) / wagg bf16[16][776] (ph2->ph3) / cagg bf16[16][264] (ph4->ph5)
__global__ __launch_bounds__(512, 4) void stftr_mega(
    const float* __restrict__ ptsf, const float* __restrict__ ptspe,
    const float* __restrict__ knnf, const float* __restrict__ knnpe,
    const float* __restrict__ sfeat, const int* __restrict__ maskp,
    const bf16x8* __restrict__ qk3pk, const bf16x8* __restrict__ wbigpk,
    const bf16x8* __restrict__ wvocpk,
    const float* __restrict__ bqk, const float* __restrict__ bbig,
    const float* __restrict__ bvoc,
    float* __restrict__ out) {
  __shared__ char shA[25088];
  __shared__ char shB[24832];
  __shared__ int vlds[VB];
  const int t = threadIdx.x, lane = t & 63, w = t >> 6;
  const int g0 = blockIdx.x * VB;

  // phase 1a: stage qb = ptsf+ptspe as bf16 into shB
  {
    uint* qb_u = (uint*)shB;
    const float4* a4 = (const float4*)(ptsf + (size_t)g0 * CC);
    const float4* b4 = (const float4*)(ptspe + (size_t)g0 * CC);
    #pragma unroll
    for (int it = 0; it < 2; ++it) {
      const int idx = it * 512 + t;
      const int row = idx >> 6, c4 = idx & 63;
      const float4 va = a4[idx], vb = b4[idx];
      qb_u[row * 132 + c4 * 2]     = bfpack(va.x + vb.x, va.y + vb.y);
      qb_u[row * 132 + c4 * 2 + 1] = bfpack(va.z + vb.z, va.w + vb.w);
    }
  }
  __syncthreads();
  // phase 1b: U = qb @ Wqk3 + bqk  (N=768) -> shA
  {
    f32x4 acc[6];
    #pragma unroll
    for (int nb = 0; nb < 6; ++nb) acc[nb] = (f32x4){0.f, 0.f, 0.f, 0.f};
    const char* qbase = shB + (lane & 15) * 528 + (lane >> 4) * 16;
    #pragma unroll
    for (int kb = 0; kb < 8; ++kb) {
      const bf16x8 a = *(const bf16x8*)(qbase + kb * 64);
      #pragma unroll
      for (int nb = 0; nb < 6; ++nb) {
        const bf16x8 bb = qk3pk[((w * 6 + nb) * 8 + kb) * 64 + lane];
        acc[nb] = mfma16(a, bb, acc[nb]);
      }
    }
    ushort* us = (ushort*)shA;
    #pragma unroll
    for (int nb = 0; nb < 6; ++nb) {
      const int n = (w * 6 + nb) * 16 + (lane & 15);
      const float bias = bqk[n];
      #pragma unroll
      for (int r = 0; r < 4; ++r) {
        const int row = (lane >> 4) * 4 + r;
        us[row * 776 + n] = (ushort)f2bf(acc[nb][r] + bias);
      }
    }
  }
  __syncthreads();
  // phase 2: 48 temporal score tasks (s,j); wave w handles 6
  {
    const uint* Au = (const uint*)shA;
    uint* Bu = (uint*)shB;
    const fvec4* kfp = (const fvec4*)knnf;
    const fvec4* kpp = (const fvec4*)knnpe;
    #pragma unroll
    for (int q = 0; q < 6; ++q) {
      const int tid = w * 6 + q;
      const int s = tid >> 4, j = tid & 15;
      const size_t rb = ((size_t)(s * NVOX + g0 + j)) * 512 + lane;
      fvec4 sm[KK];
      #pragma unroll
      for (int r = 0; r < KK; ++r) {
        const fvec4 kf = __builtin_nontemporal_load(&kfp[rb + r * 64]);
        const fvec4 kp = __builtin_nontemporal_load(&kpp[rb + r * 64]);
        sm[r] = kf + kp;
      }
      const uint ua = Au[j * 388 + s * 128 + lane * 2];
      const uint ub = Au[j * 388 + s * 128 + lane * 2 + 1];
      const float u0 = bflo(ua), u1 = bfhi(ua), u2 = bflo(ub), u3 = bfhi(ub);
      float sc[KK];
      #pragma unroll
      for (int r = 0; r < KK; ++r) {
        float p = sm[r].x * u0 + sm[r].y * u1 + sm[r].z * u2 + sm[r].w * u3;
        sc[r] = wred(p);
      }
      float mx = sc[0];
      #pragma unroll
      for (int r = 1; r < KK; ++r) mx = fmaxf(mx, sc[r]);
      float e[KK], sum = 0.f;
      #pragma unroll
      for (int r = 0; r < KK; ++r) { e[r] = __expf((sc[r] - mx) * 0.0625f); sum += e[r]; }
      const float inv = 1.f / sum;
      fvec4 acc = (fvec4){0.f, 0.f, 0.f, 0.f};
      #pragma unroll
      for (int r = 0; r < KK; ++r) acc += (e[r] * inv) * sm[r];
      Bu[j * 388 + s * 128 + lane * 2]     = bfpack(acc.x, acc.y);
      Bu[j * 388 + s * 128 + lane * 2 + 1] = bfpack(acc.z, acc.w);
    }
  }
  __syncthreads();
  // phase 3: Uc = wagg_cat @ Wbig + bbig  (K=768, N=256) -> shA
  {
    f32x4 acc[2];
    acc[0] = (f32x4){0.f, 0.f, 0.f, 0.f};
    acc[1] = (f32x4){0.f, 0.f, 0.f, 0.f};
    const char* abase = shB + (lane & 15) * 1552 + (lane >> 4) * 16;
    #pragma unroll 4
    for (int kb = 0; kb < 24; ++kb) {
      const bf16x8 a = *(const bf16x8*)(abase + kb * 64);
      #pragma unroll
      for (int nb = 0; nb < 2; ++nb) {
        const bf16x8 bb = wbigpk[((w * 2 + nb) * 24 + kb) * 64 + lane];
        acc[nb] = mfma16(a, bb, acc[nb]);
      }
    }
    ushort* ust = (ushort*)shA;
    #pragma unroll
    for (int nb = 0; nb < 2; ++nb) {
      const int n = (w * 2 + nb) * 16 + (lane & 15);
      const float bias = bbig[n];
      #pragma unroll
      for (int r = 0; r < 4; ++r) {
        const int row = (lane >> 4) * 4 + r;
        ust[row * 264 + n] = (ushort)f2bf(acc[nb][r] + bias);
      }
    }
  }
  __syncthreads();
  // phase 4: cross-sensor score tasks; wave w handles 2
  {
    const uint* Au = (const uint*)shA;
    uint* Bu = (uint*)shB;
    const float4* sfp = (const float4*)sfeat;
    #pragma unroll
    for (int jj = 0; jj < 2; ++jj) {
      const int j = w * 2 + jj;
      const int g = g0 + j;
      const uint ua = Au[j * 132 + lane * 2];
      const uint ub = Au[j * 132 + lane * 2 + 1];
      const float u0 = bflo(ua), u1 = bfhi(ua), u2 = bflo(ub), u3 = bfhi(ub);
      const size_t sb = (size_t)g * (MM * 64) + lane;
      float4 sf[MM]; float scm[MM]; int anyv = 0;
      #pragma unroll
      for (int m = 0; m < MM; ++m) {
        sf[m] = sfp[sb + m * 64];
        const int mk = maskp[(size_t)g * MM + m];
        anyv |= mk;
        float p = sf[m].x * u0 + sf[m].y * u1 + sf[m].z * u2 + sf[m].w * u3;
        p = wred(p);
        scm[m] = mk ? p * 0.0625f : -1e9f;
      }
      float mx = scm[0];
      #pragma unroll
      for (int m = 1; m < MM; ++m) mx = fmaxf(mx, scm[m]);
      float e[MM], sum = 0.f;
      #pragma unroll
      for (int m = 0; m < MM; ++m) { e[m] = __expf(scm[m] - mx); sum += e[m]; }
      const float inv = 1.f / sum;
      float4 ag = make_float4(0.f, 0.f, 0.f, 0.f);
      #pragma unroll
      for (int m = 0; m < MM; ++m) {
        const float a = e[m] * inv;
        ag.x += a * sf[m].x; ag.y += a * sf[m].y;
        ag.z += a * sf[m].z; ag.w += a * sf[m].w;
      }
      Bu[j * 132 + lane * 2]     = bfpack(ag.x, ag.y);
      Bu[j * 132 + lane * 2 + 1] = bfpack(ag.z, ag.w);
      if (lane == 0) vlds[j] = anyv;
    }
  }
  __syncthreads();
  // phase 5: out = cagg @ Wvoc + bvoc -> Ost (shA+8448)
  {
    f32x4 acc[2];
    acc[0] = (f32x4){0.f, 0.f, 0.f, 0.f};
    acc[1] = (f32x4){0.f, 0.f, 0.f, 0.f};
    const char* cbase = shB + (lane & 15) * 528 + (lane >> 4) * 16;
    #pragma unroll
    for (int kb = 0; kb < 8; ++kb) {
      const bf16x8 a = *(const bf16x8*)(cbase + kb * 64);
      #pragma unroll
      for (int nb = 0; nb < 2; ++nb) {
        const bf16x8 bb = wvocpk[((w * 2 + nb) * 8 + kb) * 64 + lane];
        acc[nb] = mfma16(a, bb, acc[nb]);
      }
    }
    float* ost = (float*)(shA + 8448);
    #pragma unroll
    for (int nb = 0; nb < 2; ++nb) {
      const int n = (w * 2 + nb) * 16 + (lane & 15);
      const float bias = bvoc[n];
      #pragma unroll
      for (int r = 0; r < 4; ++r) {
        const int row = (lane >> 4) * 4 + r;
        ost[row * 260 + n] = acc[nb][r] + bias;
      }
    }
  }
  __syncthreads();
  {
    const float* ost = (const float*)(shA + 8448);
    #pragma unroll
    for (int it = 0; it < 8; ++it) {
      const int idx = it * 512 + t;
      const int row = idx >> 8, d = idx & 255;
      out[((size_t)(g0 + row)) * 256 + d] = vlds[row] ? ost[row * 260 + d] : 0.f;
    }
  }
}

extern "C" void kernel_launch(void* const* d_in, const int* in_sizes, int n_in,
                              void* d_out, int out_size, void* d_ws, size_t ws_size,
                              hipStream_t stream) {
  const float* ptsf  = (const float*)d_in[0];
  const float* ptspe = (const float*)d_in[1];
  const float* knnf  = (const float*)d_in[2];
  const float* knnpe = (const float*)d_in[3];
  const float* sfeat = (const float*)d_in[4];
  const int*   maskp = (const int*)d_in[5];
  const float* Wq_t = (const float*)d_in[6];
  const float* Wk_t = (const float*)d_in[7];
  const float* Wv_t = (const float*)d_in[8];
  const float* Wo_t = (const float*)d_in[9];
  const float* bq_t = (const float*)d_in[10];
  const float* bv_t = (const float*)d_in[12];
  const float* bo_t = (const float*)d_in[13];
  const float* Wq_c = (const float*)d_in[14];
  const float* Wk_c = (const float*)d_in[15];
  const float* Wv_c = (const float*)d_in[16];
  const float* Wo_c = (const float*)d_in[17];
  const float* bq_c = (const float*)d_in[18];
  const float* bv_c = (const float*)d_in[20];
  const float* bo_c = (const float*)d_in[21];
  // bk_t/bk_c unused: folded score constants are softmax-shift-invariant

  if (ws_size < WS_NEED) return;
  char* ws = (char*)d_ws;
  float* Wqkf3  = (float*)(ws + OFF_WQKF3);
  float* Wvof   = (float*)(ws + OFF_WVOF);
  float* bqk    = (float*)(ws + OFF_BQK);
  float* bvo    = (float*)(ws + OFF_BVO);
  float* bbig   = (float*)(ws + OFF_BBIG);
  uint4* qk3pk  = (uint4*)(ws + OFF_QK3PK);
  uint4* wbigpk = (uint4*)(ws + OFF_WBIGPK);
  uint4* wvocpk = (uint4*)(ws + OFF_WVOCPK);

  prep_fold_all<<<260, 256, 0, stream>>>(
      Wq_t, Wq_c, Wk_t, Wk_c, Wv_t, Wv_c, Wo_t, Wo_c,
      bq_t, bq_c, bv_t, bv_c, bo_t, bo_c,
      Wqkf3, Wvof, bqk, bvo, qk3pk, wvocpk);
  prep_wbig2<<<97, 256, 0, stream>>>(Wvof, Wqkf3, bqk, bvo, wbigpk, bbig);

  stftr_mega<<<NBLK, 512, 0, stream>>>(
      ptsf, ptspe, knnf, knnpe, sfeat, maskp,
      (const bf16x8*)qk3pk, (const bf16x8*)wbigpk, (const bf16x8*)wvocpk,
      bqk, bbig, bvo + 3 * 256, (float*)d_out);
}

// Round 8
// 170.185 us; speedup vs baseline: 12.3366x; 1.0060x over previous
//
#include <hip/hip_runtime.h>
#include <math.h>

#define CC 256
#define KK 8
#define MM 6
#define SS 3
#define NVOX 12000
#define VB 16
#define NBLK (NVOX / VB)

typedef __attribute__((ext_vector_type(8))) short bf16x8;
typedef __attribute__((ext_vector_type(4))) float f32x4;
typedef __attribute__((ext_vector_type(4))) float fvec4;

// ---- ws layout (bytes) ----
#define OFF_QK3PK  0u           // uint4 [48ng][8kb][64lane]
#define OFF_WBIGPK 393216u      // uint4 [16ng][24kb][64lane]
#define OFF_WVOCPK 786432u      // uint4 [16ng][8kb][64lane]
#define OFF_BQK    917504u      // f32 [3][256]
#define OFF_BBIG   920576u      // f32 [256]
#define OFF_BVOC   921600u      // f32 [256]
#define WS_NEED    922624u

__device__ __forceinline__ float wred(float p) {
  #pragma unroll
  for (int off = 32; off; off >>= 1) p += __shfl_xor(p, off, 64);
  return p;
}
__device__ __forceinline__ uint f2bf(float x) {  // RNE to bf16 bits
  const uint u = __float_as_uint(x);
  return (u + 0x7fffu + ((u >> 16) & 1u)) >> 16;
}
__device__ __forceinline__ uint bfpack(float a, float b) {
  return (f2bf(b) << 16) | f2bf(a);
}
__device__ __forceinline__ float bflo(uint w) { return __uint_as_float(w << 16); }
__device__ __forceinline__ float bfhi(uint w) { return __uint_as_float(w & 0xffff0000u); }

__device__ __forceinline__ f32x4 mfma16(bf16x8 a, bf16x8 b, f32x4 c) {
  return __builtin_amdgcn_mfma_f32_16x16x32_bf16(a, b, c, 0, 0, 0);
}

// ---------------- single prep kernel: all folds, packed outputs ----------------
// b<96: qk3pk (u=b>>5); 96<=b<192: chained Wbig rows; 192<=b<224: wvocpk;
// 224<=b<227: bqk[u]; b=227: bbig + bvoc.
__global__ __launch_bounds__(256) void prep_all(
    const float* __restrict__ Wq_t, const float* __restrict__ Wq_c,
    const float* __restrict__ Wk_t, const float* __restrict__ Wk_c,
    const float* __restrict__ Wv_t, const float* __restrict__ Wv_c,
    const float* __restrict__ Wo_t, const float* __restrict__ Wo_c,
    const float* __restrict__ bq_t, const float* __restrict__ bq_c,
    const float* __restrict__ bv_t, const float* __restrict__ bv_c,
    const float* __restrict__ bo_t, const float* __restrict__ bo_c,
    uint4* __restrict__ qk3pk, uint4* __restrict__ wbigpk,
    uint4* __restrict__ wvocpk,
    float* __restrict__ bqk, float* __restrict__ bbig,
    float* __restrict__ bvoc) {
  const int b = blockIdx.x, t = threadIdx.x;
  __shared__ float xl[8][256];
  if (b < 96) {
    const int u = b >> 5, c0 = (b & 31) * 8;
    const float* Wq = Wq_t + u * 65536;
    const float* Wk = Wk_t + u * 65536;
    #pragma unroll
    for (int i = 0; i < 8; ++i) xl[i][t] = Wq[(c0 + i) * 256 + t];
    __syncthreads();
    float acc[8] = {0.f, 0.f, 0.f, 0.f, 0.f, 0.f, 0.f, 0.f};
    const float4* wr = (const float4*)(Wk + t * 256);
    #pragma unroll 4
    for (int d4 = 0; d4 < 64; ++d4) {
      const float4 wv = wr[d4];
      #pragma unroll
      for (int j = 0; j < 8; ++j)
        acc[j] += xl[j][d4 * 4] * wv.x + xl[j][d4 * 4 + 1] * wv.y +
                  xl[j][d4 * 4 + 2] * wv.z + xl[j][d4 * 4 + 3] * wv.w;
    }
    const int lane = (((c0 >> 3) & 3) << 4) | (t & 15);
    uint4 o;
    o.x = bfpack(acc[0], acc[1]); o.y = bfpack(acc[2], acc[3]);
    o.z = bfpack(acc[4], acc[5]); o.w = bfpack(acc[6], acc[7]);
    qk3pk[((u * 16 + (t >> 4)) * 8 + (c0 >> 5)) * 64 + lane] = o;
  } else if (b < 192) {
    const int v = (b - 96) >> 5, bi = (b - 96) & 31;
    const int c0 = bi * 8, row0 = v * 256 + c0;
    const float* Wv = Wv_t + v * 65536;
    const float* Wo = Wo_t + v * 65536;
    #pragma unroll
    for (int i = 0; i < 8; ++i) xl[i][t] = Wv[(c0 + i) * 256 + t];
    __syncthreads();
    float a1[8] = {0.f, 0.f, 0.f, 0.f, 0.f, 0.f, 0.f, 0.f};
    #pragma unroll 4
    for (int d = 0; d < 256; ++d) {
      const float w = Wo[d * 256 + t];
      #pragma unroll
      for (int j = 0; j < 8; ++j) a1[j] += xl[j][d] * w;
    }
    __syncthreads();
    #pragma unroll
    for (int j = 0; j < 8; ++j) xl[j][t] = a1[j];
    __syncthreads();
    float a2[8] = {0.f, 0.f, 0.f, 0.f, 0.f, 0.f, 0.f, 0.f};
    #pragma unroll 4
    for (int d = 0; d < 256; ++d) {
      const float w = Wq_c[d * 256 + t];
      #pragma unroll
      for (int j = 0; j < 8; ++j) a2[j] += xl[j][d] * w;
    }
    __syncthreads();
    #pragma unroll
    for (int j = 0; j < 8; ++j) xl[j][t] = a2[j];
    __syncthreads();
    float a3[8] = {0.f, 0.f, 0.f, 0.f, 0.f, 0.f, 0.f, 0.f};
    const float4* wr = (const float4*)(Wk_c + t * 256);
    #pragma unroll 4
    for (int d4 = 0; d4 < 64; ++d4) {
      const float4 wv = wr[d4];
      #pragma unroll
      for (int j = 0; j < 8; ++j)
        a3[j] += xl[j][d4 * 4] * wv.x + xl[j][d4 * 4 + 1] * wv.y +
                 xl[j][d4 * 4 + 2] * wv.z + xl[j][d4 * 4 + 3] * wv.w;
    }
    const int lane = (((row0 >> 3) & 3) << 4) | (t & 15);
    uint4 o;
    o.x = bfpack(a3[0], a3[1]); o.y = bfpack(a3[2], a3[3]);
    o.z = bfpack(a3[4], a3[5]); o.w = bfpack(a3[6], a3[7]);
    wbigpk[((t >> 4) * 24 + (row0 >> 5)) * 64 + lane] = o;
  } else if (b < 224) {
    const int c0 = (b - 192) * 8;
    #pragma unroll
    for (int i = 0; i < 8; ++i) xl[i][t] = Wv_c[(c0 + i) * 256 + t];
    __syncthreads();
    float acc[8] = {0.f, 0.f, 0.f, 0.f, 0.f, 0.f, 0.f, 0.f};
    #pragma unroll 4
    for (int d = 0; d < 256; ++d) {
      const float w = Wo_c[d * 256 + t];
      #pragma unroll
      for (int j = 0; j < 8; ++j) acc[j] += xl[j][d] * w;
    }
    const int lane = (((c0 >> 3) & 3) << 4) | (t & 15);
    uint4 o;
    o.x = bfpack(acc[0], acc[1]); o.y = bfpack(acc[2], acc[3]);
    o.z = bfpack(acc[4], acc[5]); o.w = bfpack(acc[6], acc[7]);
    wvocpk[((t >> 4) * 8 + (c0 >> 5)) * 64 + lane] = o;
  } else if (b < 227) {
    const int u = b - 224;
    xl[0][t] = bq_t[u * 256 + t];
    __syncthreads();
    const float4* wr = (const float4*)(Wk_t + u * 65536 + t * 256);
    float a = 0.f;
    #pragma unroll 4
    for (int d4 = 0; d4 < 64; ++d4) {
      const float4 wv = wr[d4];
      a += xl[0][d4 * 4] * wv.x + xl[0][d4 * 4 + 1] * wv.y +
           xl[0][d4 * 4 + 2] * wv.z + xl[0][d4 * 4 + 3] * wv.w;
    }
    bqk[u * 256 + t] = a;
  } else {
    xl[0][t] = bv_t[t]; xl[1][t] = bv_t[256 + t];
    xl[2][t] = bv_t[512 + t]; xl[3][t] = bv_c[t];
    __syncthreads();
    float bvs = bo_t[t] + bo_t[256 + t] + bo_t[512 + t];
    float bvc = bo_c[t];
    #pragma unroll 2
    for (int d = 0; d < 256; ++d) {
      bvs += xl[0][d] * Wo_t[d * 256 + t] +
             xl[1][d] * Wo_t[65536 + d * 256 + t] +
             xl[2][d] * Wo_t[131072 + d * 256 + t];
      bvc += xl[3][d] * Wo_c[d * 256 + t];
    }
    bvoc[t] = bvc;
    __syncthreads();
    xl[4][t] = bvs;
    __syncthreads();
    float y = bq_c[t];
    #pragma unroll 4
    for (int d = 0; d < 256; ++d) y += xl[4][d] * Wq_c[d * 256 + t];
    __syncthreads();
    xl[5][t] = y;
    __syncthreads();
    const float4* wr = (const float4*)(Wk_c + t * 256);
    float bb = 0.f;
    #pragma unroll 4
    for (int d4 = 0; d4 < 64; ++d4) {
      const float4 wv = wr[d4];
      bb += xl[5][d4 * 4] * wv.x + xl[5][d4 * 4 + 1] * wv.y +
            xl[5][d4 * 4 + 2] * wv.z + xl[5][d4 * 4 + 3] * wv.w;
    }
    bbig[t] = bb;
  }
}

// ---------------- mega kernel: whole per-voxel pipeline, intermediates in LDS ----------------
// shA: U bf16[16][776] (ph1->ph2) / Uc bf16[16][264] (ph3->ph4) / Ost f32[16][260]@8448 (ph5)
// shB: qb bf16[16][264] (ph1) / wagg bf16[16][776] (ph2->ph3) / cagg bf16[16][264] (ph4->ph5)
__global__ __launch_bounds__(512, 6) void stftr_mega(
    const float* __restrict__ ptsf, const float* __restrict__ ptspe,
    const float* __restrict__ knnf, const float* __restrict__ knnpe,
    const float* __restrict__ sfeat, const int* __restrict__ maskp,
    const bf16x8* __restrict__ qk3pk, const bf16x8* __restrict__ wbigpk,
    const bf16x8* __restrict__ wvocpk,
    const float* __restrict__ bqk, const float* __restrict__ bbig,
    const float* __restrict__ bvoc,
    float* __restrict__ out) {
  __shared__ char shA[25088];
  __shared__ char shB[24832];
  __shared__ int mlds[VB * MM];
  __shared__ int vlds[VB];
  const int t = threadIdx.x, lane = t & 63, w = t >> 6;
  const int g0 = blockIdx.x * VB;

  // phase 1a: stage qb = ptsf+ptspe as bf16 into shB ; preload mask
  {
    uint* qb_u = (uint*)shB;
    const fvec4* a4 = (const fvec4*)(ptsf + (size_t)g0 * CC);
    const fvec4* b4 = (const fvec4*)(ptspe + (size_t)g0 * CC);
    #pragma unroll
    for (int it = 0; it < 2; ++it) {
      const int idx = it * 512 + t;
      const int row = idx >> 6, c4 = idx & 63;
      const fvec4 va = __builtin_nontemporal_load(&a4[idx]);
      const fvec4 vb = __builtin_nontemporal_load(&b4[idx]);
      qb_u[row * 132 + c4 * 2]     = bfpack(va.x + vb.x, va.y + vb.y);
      qb_u[row * 132 + c4 * 2 + 1] = bfpack(va.z + vb.z, va.w + vb.w);
    }
    if (t < VB * MM) mlds[t] = maskp[g0 * MM + t];
  }
  __syncthreads();
  // phase 1b: U = qb @ Wqk3 + bqk  (N=768) -> shA
  {
    f32x4 acc[6];
    #pragma unroll
    for (int nb = 0; nb < 6; ++nb) acc[nb] = (f32x4){0.f, 0.f, 0.f, 0.f};
    const char* qbase = shB + (lane & 15) * 528 + (lane >> 4) * 16;
    #pragma unroll
    for (int kb = 0; kb < 8; ++kb) {
      const bf16x8 a = *(const bf16x8*)(qbase + kb * 64);
      #pragma unroll
      for (int nb = 0; nb < 6; ++nb) {
        const bf16x8 bb = qk3pk[((w * 6 + nb) * 8 + kb) * 64 + lane];
        acc[nb] = mfma16(a, bb, acc[nb]);
      }
    }
    ushort* us = (ushort*)shA;
    #pragma unroll
    for (int nb = 0; nb < 6; ++nb) {
      const int n = (w * 6 + nb) * 16 + (lane & 15);
      const float bias = bqk[n];
      #pragma unroll
      for (int r = 0; r < 4; ++r) {
        const int row = (lane >> 4) * 4 + r;
        us[row * 776 + n] = (ushort)f2bf(acc[nb][r] + bias);
      }
    }
  }
  __syncthreads();
  // phase 2: 48 temporal score tasks (s,j); wave w handles 6 sequentially
  {
    const uint* Au = (const uint*)shA;
    uint* Bu = (uint*)shB;
    const fvec4* kfp = (const fvec4*)knnf;
    const fvec4* kpp = (const fvec4*)knnpe;
    for (int q = 0; q < 6; ++q) {
      const int tid = w * 6 + q;
      const int s = tid >> 4, j = tid & 15;
      const size_t rb = ((size_t)(s * NVOX + g0 + j)) * 512 + lane;
      fvec4 sm[KK];
      #pragma unroll
      for (int r = 0; r < KK; ++r) {
        const fvec4 kf = __builtin_nontemporal_load(&kfp[rb + r * 64]);
        const fvec4 kp = __builtin_nontemporal_load(&kpp[rb + r * 64]);
        sm[r] = kf + kp;
      }
      const uint ua = Au[j * 388 + s * 128 + lane * 2];
      const uint ub = Au[j * 388 + s * 128 + lane * 2 + 1];
      const float u0 = bflo(ua), u1 = bfhi(ua), u2 = bflo(ub), u3 = bfhi(ub);
      float sc[KK];
      #pragma unroll
      for (int r = 0; r < KK; ++r) {
        float p = sm[r].x * u0 + sm[r].y * u1 + sm[r].z * u2 + sm[r].w * u3;
        sc[r] = wred(p);
      }
      float mx = sc[0];
      #pragma unroll
      for (int r = 1; r < KK; ++r) mx = fmaxf(mx, sc[r]);
      float e[KK], sum = 0.f;
      #pragma unroll
      for (int r = 0; r < KK; ++r) { e[r] = __expf((sc[r] - mx) * 0.0625f); sum += e[r]; }
      const float inv = 1.f / sum;
      fvec4 acc = (fvec4){0.f, 0.f, 0.f, 0.f};
      #pragma unroll
      for (int r = 0; r < KK; ++r) acc += (e[r] * inv) * sm[r];
      Bu[j * 388 + s * 128 + lane * 2]     = bfpack(acc.x, acc.y);
      Bu[j * 388 + s * 128 + lane * 2 + 1] = bfpack(acc.z, acc.w);
    }
  }
  __syncthreads();
  // phase 3: Uc = wagg_cat @ Wbig + bbig  (K=768, N=256) -> shA
  {
    f32x4 acc[2];
    acc[0] = (f32x4){0.f, 0.f, 0.f, 0.f};
    acc[1] = (f32x4){0.f, 0.f, 0.f, 0.f};
    const char* abase = shB + (lane & 15) * 1552 + (lane >> 4) * 16;
    #pragma unroll 4
    for (int kb = 0; kb < 24; ++kb) {
      const bf16x8 a = *(const bf16x8*)(abase + kb * 64);
      #pragma unroll
      for (int nb = 0; nb < 2; ++nb) {
        const bf16x8 bb = wbigpk[((w * 2 + nb) * 24 + kb) * 64 + lane];
        acc[nb] = mfma16(a, bb, acc[nb]);
      }
    }
    ushort* ust = (ushort*)shA;
    #pragma unroll
    for (int nb = 0; nb < 2; ++nb) {
      const int n = (w * 2 + nb) * 16 + (lane & 15);
      const float bias = bbig[n];
      #pragma unroll
      for (int r = 0; r < 4; ++r) {
        const int row = (lane >> 4) * 4 + r;
        ust[row * 264 + n] = (ushort)f2bf(acc[nb][r] + bias);
      }
    }
  }
  __syncthreads();
  // phase 4: cross-sensor score tasks; wave w handles 2
  {
    const uint* Au = (const uint*)shA;
    uint* Bu = (uint*)shB;
    const fvec4* sfp = (const fvec4*)sfeat;
    #pragma unroll
    for (int jj = 0; jj < 2; ++jj) {
      const int j = w * 2 + jj;
      const int g = g0 + j;
      const uint ua = Au[j * 132 + lane * 2];
      const uint ub = Au[j * 132 + lane * 2 + 1];
      const float u0 = bflo(ua), u1 = bfhi(ua), u2 = bflo(ub), u3 = bfhi(ub);
      const size_t sb = (size_t)g * (MM * 64) + lane;
      fvec4 sf[MM]; float scm[MM]; int anyv = 0;
      #pragma unroll
      for (int m = 0; m < MM; ++m) {
        sf[m] = __builtin_nontemporal_load(&sfp[sb + m * 64]);
        const int mk = mlds[j * MM + m];
        anyv |= mk;
        float p = sf[m].x * u0 + sf[m].y * u1 + sf[m].z * u2 + sf[m].w * u3;
        p = wred(p);
        scm[m] = mk ? p * 0.0625f : -1e9f;
      }
      float mx = scm[0];
      #pragma unroll
      for (int m = 1; m < MM; ++m) mx = fmaxf(mx, scm[m]);
      float e[MM], sum = 0.f;
      #pragma unroll
      for (int m = 0; m < MM; ++m) { e[m] = __expf(scm[m] - mx); sum += e[m]; }
      const float inv = 1.f / sum;
      fvec4 ag = (fvec4){0.f, 0.f, 0.f, 0.f};
      #pragma unroll
      for (int m = 0; m < MM; ++m) ag += (e[m] * inv) * sf[m];
      Bu[j * 132 + lane * 2]     = bfpack(ag.x, ag.y);
      Bu[j * 132 + lane * 2 + 1] = bfpack(ag.z, ag.w);
      if (lane == 0) vlds[j] = anyv;
    }
  }
  __syncthreads();
  // phase 5: out = cagg @ Wvoc + bvoc -> Ost (shA+8448)
  {
    f32x4 acc[2];
    acc[0] = (f32x4){0.f, 0.f, 0.f, 0.f};
    acc[1] = (f32x4){0.f, 0.f, 0.f, 0.f};
    const char* cbase = shB + (lane & 15) * 528 + (lane >> 4) * 16;
    #pragma unroll
    for (int kb = 0; kb < 8; ++kb) {
      const bf16x8 a = *(const bf16x8*)(cbase + kb * 64);
      #pragma unroll
      for (int nb = 0; nb < 2; ++nb) {
        const bf16x8 bb = wvocpk[((w * 2 + nb) * 8 + kb) * 64 + lane];
        acc[nb] = mfma16(a, bb, acc[nb]);
      }
    }
    float* ost = (float*)(shA + 8448);
    #pragma unroll
    for (int nb = 0; nb < 2; ++nb) {
      const int n = (w * 2 + nb) * 16 + (lane & 15);
      const float bias = bvoc[n];
      #pragma unroll
      for (int r = 0; r < 4; ++r) {
        const int row = (lane >> 4) * 4 + r;
        ost[row * 260 + n] = acc[nb][r] + bias;
      }
    }
  }
  __syncthreads();
  {
    const float* ost = (const float*)(shA + 8448);
    #pragma unroll
    for (int it = 0; it < 8; ++it) {
      const int idx = it * 512 + t;
      const int row = idx >> 8, d = idx & 255;
      const float v = vlds[row] ? ost[row * 260 + d] : 0.f;
      __builtin_nontemporal_store(v, &out[((size_t)(g0 + row)) * 256 + d]);
    }
  }
}

extern "C" void kernel_launch(void* const* d_in, const int* in_sizes, int n_in,
                              void* d_out, int out_size, void* d_ws, size_t ws_size,
                              hipStream_t stream) {
  const float* ptsf  = (const float*)d_in[0];
  const float* ptspe = (const float*)d_in[1];
  const float* knnf  = (const float*)d_in[2];
  const float* knnpe = (const float*)d_in[3];
  const float* sfeat = (const float*)d_in[4];
  const int*   maskp = (const int*)d_in[5];
  const float* Wq_t = (const float*)d_in[6];
  const float* Wk_t = (const float*)d_in[7];
  const float* Wv_t = (const float*)d_in[8];
  const float* Wo_t = (const float*)d_in[9];
  const float* bq_t = (const float*)d_in[10];
  const float* bv_t = (const float*)d_in[12];
  const float* bo_t = (const float*)d_in[13];
  const float* Wq_c = (const float*)d_in[14];
  const float* Wk_c = (const float*)d_in[15];
  const float* Wv_c = (const float*)d_in[16];
  const float* Wo_c = (const float*)d_in[17];
  const float* bq_c = (const float*)d_in[18];
  const float* bv_c = (const float*)d_in[20];
  const float* bo_c = (const float*)d_in[21];
  // bk_t/bk_c unused: folded score constants are softmax-shift-invariant

  if (ws_size < WS_NEED) return;
  char* ws = (char*)d_ws;
  uint4* qk3pk  = (uint4*)(ws + OFF_QK3PK);
  uint4* wbigpk = (uint4*)(ws + OFF_WBIGPK);
  uint4* wvocpk = (uint4*)(ws + OFF_WVOCPK);
  float* bqk    = (float*)(ws + OFF_BQK);
  float* bbig   = (float*)(ws + OFF_BBIG);
  float* bvoc   = (float*)(ws + OFF_BVOC);

  prep_all<<<228, 256, 0, stream>>>(
      Wq_t, Wq_c, Wk_t, Wk_c, Wv_t, Wv_c, Wo_t, Wo_c,
      bq_t, bq_c, bv_t, bv_c, bo_t, bo_c,
      qk3pk, wbigpk, wvocpk, bqk, bbig, bvoc);

  stftr_mega<<<NBLK, 512, 0, stream>>>(
      ptsf, ptspe, knnf, knnpe, sfeat, maskp,
      (const bf16x8*)qk3pk, (const bf16x8*)wbigpk, (const bf16x8*)wvocpk,
      bqk, bbig, bvoc, (float*)d_out);
}